// Round 21
// baseline (492.596 us; speedup 1.0000x reference)
//
#include <hip/hip_runtime.h>
#include <hip/hip_bf16.h>
#include <float.h>
#include <math.h>

constexpr int B = 8192;
constexpr int D = 512;
constexpr int KNN = 32;
constexpr int GROW = D / 4;  // packed int8x4 words per row

typedef __attribute__((ext_vector_type(8))) short bhalf8;
typedef __attribute__((ext_vector_type(4))) float floatx4;

#if defined(__has_builtin)
#if __has_builtin(__builtin_amdgcn_global_load_lds)
#define HAS_GLD 1
#else
#define HAS_GLD 0
#endif
#else
#define HAS_GLD 0
#endif

__device__ __forceinline__ unsigned short f2bf(float f) {
    __hip_bfloat16 h = __float2bfloat16(f);
    return __builtin_bit_cast(unsigned short, h);
}

__device__ __forceinline__ float bf2f(unsigned short u) {
    unsigned int x = ((unsigned int)u) << 16;
    return __builtin_bit_cast(float, x);
}

__device__ __forceinline__ unsigned short f2h(float f) {
    _Float16 h = (_Float16)f;
    return __builtin_bit_cast(unsigned short, h);
}

__device__ __forceinline__ float h2f(unsigned short u) {
    _Float16 h = __builtin_bit_cast(_Float16, u);
    return (float)h;
}

__device__ __forceinline__ float waveReduceSum(float v) {
#pragma unroll
    for (int off = 32; off; off >>= 1) v += __shfl_down(v, off);
    return v;
}

__device__ __forceinline__ float waveReduceMax(float v) {
#pragma unroll
    for (int off = 32; off; off >>= 1) v = fmaxf(v, __shfl_down(v, off));
    return v;
}

__device__ __forceinline__ int waveReduceSumI(int v) {
#pragma unroll
    for (int off = 32; off; off >>= 1) v += __shfl_down(v, off);
    return v;
}

// decode packed int8x4 -> float4 (linear quant; scale folded into gather weight)
__device__ __forceinline__ float4 qdec(unsigned int w) {
    float4 r;
    r.x = (float)((int)(w << 24) >> 24);
    r.y = (float)((int)(w << 16) >> 24);
    r.z = (float)((int)(w << 8) >> 24);
    r.w = (float)((int)w >> 24);
    return r;
}

__device__ __forceinline__ unsigned int qenc(float a, float b, float c, float d, float se) {
    int qx = (int)rintf(a * se); qx = max(-127, min(127, qx));
    int qy = (int)rintf(b * se); qy = max(-127, min(127, qy));
    int qz = (int)rintf(c * se); qz = max(-127, min(127, qz));
    int qw = (int)rintf(d * se); qw = max(-127, min(127, qw));
    return (unsigned int)(qx & 0xff) | ((unsigned int)(qy & 0xff) << 8) |
           ((unsigned int)(qz & 0xff) << 16) | ((unsigned int)(qw & 0xff) << 24);
}

// stage one 16B chunk of a 128x32-bf16 tile (linear LDS, 64B rows). (128^2 kernel)
__device__ __forceinline__ void stage_chunk(const unsigned short* __restrict__ g,
                                            char* __restrict__ lds_tile, int c) {
#if HAS_GLD
    char* wavebase = lds_tile + (size_t)(c & ~63) * 16;
    __builtin_amdgcn_global_load_lds((const __attribute__((address_space(1))) void*)g,
                                     (__attribute__((address_space(3))) void*)wavebase,
                                     16, 0, 0);
#else
    *(int4*)(lds_tile + (size_t)c * 16) = *(const int4*)g;
#endif
}

// C-write helper: OUTMODE 0=fp32, 1=bf16, 2=fp16. ldc in elements of the out type.
template <int OUTMODE>
__device__ __forceinline__ void cwrite(void* Cv, size_t idx, float v) {
    if (OUTMODE == 0) ((float*)Cv)[idx] = v;
    else if (OUTMODE == 1) ((unsigned short*)Cv)[idx] = f2bf(v);
    else ((unsigned short*)Cv)[idx] = f2h(v);
}

// ================= 8-phase 256x256 bf16 NT GEMM (m201-style) =================
template <int OUTMODE>
__global__ __launch_bounds__(512) void k_mfma8(
    const unsigned short* __restrict__ A, int lda,
    const unsigned short* __restrict__ Bm, int ldb,
    void* __restrict__ Cv, int ldc, int Kd) {
    __shared__ __align__(16) char lds[131072];
    constexpr int AOFF0 = 0, AOFF1 = 32768, BOFF0 = 65536, BOFF1 = 98304;

    int tid = threadIdx.x;
    int lane = tid & 63;
    int wid = tid >> 6;
    int wm = (wid >> 2) * 128;
    int wn = (wid & 3) * 64;
    int lrow = lane & 15;
    int khi = lane >> 4;
    int lk7 = lane & 7;
    int gm = blockIdx.y * 256, gn = blockIdx.x * 256;

    floatx4 zero4 = {0.0f, 0.0f, 0.0f, 0.0f};
    floatx4 acc[8][4];
#pragma unroll
    for (int m = 0; m < 8; m++)
#pragma unroll
        for (int n = 0; n < 4; n++) acc[m][n] = zero4;
    bhalf8 bfrag[4][2];

    auto stage_half = [&](const unsigned short* __restrict__ src, int ld,
                          int rowg0, int k0, int ldsbase) {
#pragma unroll
        for (int rd = 0; rd < 2; rd++) {
            int idx = rd * 512 + tid;
            int r = idx >> 3;
            int s = (idx & 7) ^ (r & 7);
            const unsigned short* g = src + (size_t)(rowg0 + r) * ld + k0 + s * 8;
#if HAS_GLD
            char* wb = lds + ldsbase + rd * 8192 + (tid >> 6) * 1024;
            __builtin_amdgcn_global_load_lds(
                (const __attribute__((address_space(1))) void*)g,
                (__attribute__((address_space(3))) void*)wb, 16, 0, 0);
#else
            *(int4*)(lds + ldsbase + (size_t)idx * 16) = *(const int4*)g;
#endif
        }
    };
    auto rdA = [&](int bufoff, int mf, int kk) -> bhalf8 {
        int r = wm + mf * 16 + lrow;
        int slot = ((kk << 2) + khi) ^ lk7;
        return *(const bhalf8*)(lds + bufoff + r * 128 + slot * 16);
    };
    auto rdB = [&](int bufoff, int nf, int kk) -> bhalf8 {
        int r = wn + nf * 16 + lrow;
        int slot = ((kk << 2) + khi) ^ lk7;
        return *(const bhalf8*)(lds + bufoff + r * 128 + slot * 16);
    };

    stage_half(A, lda, gm, 0, AOFF0);
    stage_half(A, lda, gm + 128, 0, AOFF0 + 16384);
    stage_half(Bm, ldb, gn, 0, BOFF0);
    stage_half(Bm, ldb, gn + 128, 0, BOFF0 + 16384);
    stage_half(Bm, ldb, gn, 64, BOFF1);
    stage_half(Bm, ldb, gn + 128, 64, BOFF1 + 16384);
    asm volatile("s_waitcnt vmcnt(4)" ::: "memory");
    __builtin_amdgcn_s_barrier();

#define PH(mq, AO, BO, STAGE_STMT, TAIL_STMT)                                      \
    {                                                                              \
        if ((mq) == 0) {                                                           \
            _Pragma("unroll") for (int nf = 0; nf < 4; nf++) {                     \
                bfrag[nf][0] = rdB((BO), nf, 0);                                   \
                bfrag[nf][1] = rdB((BO), nf, 1);                                   \
            }                                                                      \
        }                                                                          \
        bhalf8 a00 = rdA((AO), 2 * (mq), 0);                                       \
        bhalf8 a01 = rdA((AO), 2 * (mq), 1);                                       \
        bhalf8 a10 = rdA((AO), 2 * (mq) + 1, 0);                                   \
        bhalf8 a11 = rdA((AO), 2 * (mq) + 1, 1);                                   \
        STAGE_STMT;                                                                \
        __builtin_amdgcn_s_barrier();                                              \
        asm volatile("s_waitcnt lgkmcnt(0)" ::: "memory");                         \
        __builtin_amdgcn_sched_barrier(0);                                         \
        __builtin_amdgcn_s_setprio(1);                                             \
        _Pragma("unroll") for (int nf = 0; nf < 4; nf++) {                         \
            acc[2 * (mq)][nf] = __builtin_amdgcn_mfma_f32_16x16x32_bf16(           \
                a00, bfrag[nf][0], acc[2 * (mq)][nf], 0, 0, 0);                    \
            acc[2 * (mq) + 1][nf] = __builtin_amdgcn_mfma_f32_16x16x32_bf16(       \
                a10, bfrag[nf][0], acc[2 * (mq) + 1][nf], 0, 0, 0);                \
        }                                                                          \
        _Pragma("unroll") for (int nf = 0; nf < 4; nf++) {                         \
            acc[2 * (mq)][nf] = __builtin_amdgcn_mfma_f32_16x16x32_bf16(           \
                a01, bfrag[nf][1], acc[2 * (mq)][nf], 0, 0, 0);                    \
            acc[2 * (mq) + 1][nf] = __builtin_amdgcn_mfma_f32_16x16x32_bf16(       \
                a11, bfrag[nf][1], acc[2 * (mq) + 1][nf], 0, 0, 0);                \
        }                                                                          \
        __builtin_amdgcn_s_setprio(0);                                             \
        TAIL_STMT;                                                                 \
        __builtin_amdgcn_s_barrier();                                              \
    }

    int iters = Kd >> 7;
    for (int it = 0; it < iters; ++it) {
        bool lastI = (it == iters - 1);
        int kodd = (2 * it + 1) << 6;
        int kne = (2 * it + 2) << 6;
        int kno = (2 * it + 3) << 6;
        PH(0, AOFF0, BOFF0, stage_half(A, lda, gm, kodd, AOFF1), );
        PH(1, AOFF0, BOFF0, stage_half(A, lda, gm + 128, kodd, AOFF1 + 16384), );
        PH(2, AOFF0, BOFF0, if (!lastI) stage_half(Bm, ldb, gn, kne, BOFF0), );
        PH(3, AOFF0, BOFF0, if (!lastI) stage_half(Bm, ldb, gn + 128, kne, BOFF0 + 16384),
           if (lastI) { asm volatile("s_waitcnt vmcnt(0)" ::: "memory"); } else {
               asm volatile("s_waitcnt vmcnt(4)" ::: "memory"); });
        PH(0, AOFF1, BOFF1, if (!lastI) stage_half(A, lda, gm, kne, AOFF0), );
        PH(1, AOFF1, BOFF1, if (!lastI) stage_half(A, lda, gm + 128, kne, AOFF0 + 16384), );
        PH(2, AOFF1, BOFF1, if (!lastI) stage_half(Bm, ldb, gn, kno, BOFF1), );
        PH(3, AOFF1, BOFF1, if (!lastI) stage_half(Bm, ldb, gn + 128, kno, BOFF1 + 16384),
           if (lastI) { asm volatile("s_waitcnt vmcnt(0)" ::: "memory"); } else {
               asm volatile("s_waitcnt vmcnt(4)" ::: "memory"); });
    }
#undef PH

#pragma unroll
    for (int mf = 0; mf < 8; mf++) {
#pragma unroll
        for (int nf = 0; nf < 4; nf++) {
            int cc = gn + wn + nf * 16 + lrow;
#pragma unroll
            for (int q = 0; q < 4; q++) {
                int r = gm + wm + mf * 16 + khi * 4 + q;
                cwrite<OUTMODE>(Cv, (size_t)r * ldc + cc, acc[mf][nf][q]);
            }
        }
    }
}

// ---------------- bf16 MFMA GEMM, NT form (128^2; final GEMM + fallback) ----------
// For the split-K config (gridDim = {4, ny, nz>=8}), remap blocks so the 4 x-blocks
// sharing an A-panel (same y,z) land on the SAME XCD (lid mod 8 constant).
// Bijective: lid = (g%8) + 8*((g/8)*4 + bx), g = bz*ny + by  (requires ny*nz % 8 == 0).
template <int OUTMODE>
__global__ __launch_bounds__(256, 2) void k_mfma_nt(
    const unsigned short* __restrict__ A, int lda,
    const unsigned short* __restrict__ B1, int ldb,
    void* __restrict__ Cv, int ldc, int zstride, int ksplit) {
    __shared__ __align__(16) char smem[2 * 8192];
    char* Asm = smem;
    char* B1sm = smem + 8192;

    int tid = threadIdx.x;
    int lane = tid & 63;
    int wid = tid >> 6;
    int wm = (wid >> 1) * 64, wn = (wid & 1) * 64;
    int lrow = lane & 15;
    int kh = lane >> 4;

    int bx = blockIdx.x, by = blockIdx.y, bz = blockIdx.z;
    int ny = gridDim.y;
    if (gridDim.x == 4 && gridDim.z >= 8 && ((ny * gridDim.z) & 7) == 0) {
        int lid = bx + 4 * (by + ny * bz);  // hw dispatch linear id (x fastest)
        int xcd = lid & 7;
        int h = lid >> 3;
        bx = h & 3;
        int g = (h >> 2) * 8 + xcd;  // group = A-panel key
        by = g % ny;
        bz = g / ny;
    }
    int gm = by * 128, gn = bx * 128;
    int kbeg = bz * ksplit;
    size_t zoff = (size_t)bz * zstride;

    floatx4 zero4 = {0.0f, 0.0f, 0.0f, 0.0f};
    floatx4 acc1[4][4];
#pragma unroll
    for (int m = 0; m < 4; m++)
#pragma unroll
        for (int n = 0; n < 4; n++) acc1[m][n] = zero4;

    for (int k0 = kbeg; k0 < kbeg + ksplit; k0 += 32) {
        __syncthreads();
#pragma unroll
        for (int p = 0; p < 2; p++) {
            int c = p * 256 + tid;
            int row = c >> 2;
            int col = (c & 3) * 8;
            stage_chunk(A + (size_t)(gm + row) * lda + k0 + col, Asm, c);
            stage_chunk(B1 + (size_t)(gn + row) * ldb + k0 + col, B1sm, c);
        }
        __syncthreads();

        bhalf8 a[4];
#pragma unroll
        for (int m = 0; m < 4; m++)
            a[m] = *(const bhalf8*)(Asm + (wm + m * 16 + lrow) * 64 + kh * 16);
#pragma unroll
        for (int n = 0; n < 4; n++) {
            bhalf8 b = *(const bhalf8*)(B1sm + (wn + n * 16 + lrow) * 64 + kh * 16);
#pragma unroll
            for (int m = 0; m < 4; m++)
                acc1[m][n] = __builtin_amdgcn_mfma_f32_16x16x32_bf16(a[m], b, acc1[m][n], 0, 0, 0);
        }
    }

#pragma unroll
    for (int m = 0; m < 4; m++) {
#pragma unroll
        for (int n = 0; n < 4; n++) {
            int cc = gn + wn + n * 16 + lrow;
#pragma unroll
            for (int q = 0; q < 4; q++) {
                int r = gm + wm + m * 16 + kh * 4 + q;
                cwrite<OUTMODE>(Cv, zoff + (size_t)r * ldc + cc, acc1[m][n][q]);
            }
        }
    }
}

// ---------------- split-K reduce over fp16 partials ----------------
// partial(z, lr, d) at P16 + lr*16384 + z*512 + d  (upper 16 KB of 32 KB chunk rows)
__global__ __launch_bounds__(256) void k_redh(const unsigned short* __restrict__ P16,
                                              float* __restrict__ outp, int SK) {
    int idx = blockIdx.x * 256 + threadIdx.x;
    int lr = idx >> 7;
    int d4 = (idx & 127) * 4;
    const unsigned short* base = P16 + (size_t)lr * 16384 + d4;
    float s0 = 0, s1 = 0, s2 = 0, s3 = 0;
    for (int p = 0; p < SK; p++) {
        int2 w = *(const int2*)(base + (size_t)p * 512);
        const unsigned short* h = (const unsigned short*)&w;
        s0 += h2f(h[0]); s1 += h2f(h[1]); s2 += h2f(h[2]); s3 += h2f(h[3]);
    }
    float4 o; o.x = s0; o.y = s1; o.z = s2; o.w = s3;
    *(float4*)(outp + (size_t)lr * 512 + d4) = o;
}

// ------- normalize rows of F -> bf16 Xb, int8 Fq + fscale, invnf -------
__global__ __launch_bounds__(128) void k_norm(const float* __restrict__ F,
                                              unsigned short* __restrict__ Xb,
                                              unsigned int* __restrict__ Fq,
                                              float* __restrict__ fscale,
                                              float* __restrict__ invnf) {
    int row = blockIdx.x, tid = threadIdx.x;
    float4 v = ((const float4*)(F + (size_t)row * D))[tid];
    float ss = v.x * v.x + v.y * v.y + v.z * v.z + v.w * v.w;
    float am = fmaxf(fmaxf(fabsf(v.x), fabsf(v.y)), fmaxf(fabsf(v.z), fabsf(v.w)));
    ss = waveReduceSum(ss);
    am = waveReduceMax(am);
    __shared__ float rs[2], rm[2];
    if ((tid & 63) == 0) { rs[tid >> 6] = ss; rm[tid >> 6] = am; }
    __syncthreads();
    float inv = 1.0f / fmaxf(sqrtf(rs[0] + rs[1]), 1e-12f);
    float amax = fmaxf(rm[0], rm[1]);
    if (tid == 0) { invnf[row] = inv; fscale[row] = amax * (1.0f / 127.0f); }
    union { unsigned short s[4]; int2 q; } ux;
    ux.s[0] = f2bf(v.x * inv); ux.s[1] = f2bf(v.y * inv);
    ux.s[2] = f2bf(v.z * inv); ux.s[3] = f2bf(v.w * inv);
    *(int2*)(Xb + (size_t)row * D + tid * 4) = ux.q;
    float se = (amax > 0.0f) ? 127.0f / amax : 0.0f;
    Fq[(size_t)row * GROW + tid] = qenc(v.x, v.y, v.z, v.w, se);
}

// ---------------- transpose F (fp32 BxD) -> FbT (bf16 DxB) ----------------
__global__ __launch_bounds__(256) void k_transpose(const float* __restrict__ F,
                                                   unsigned short* __restrict__ FbT) {
    __shared__ float t[64][65];
    int r0 = blockIdx.x * 64, d0 = blockIdx.y * 64;
    int tid = threadIdx.x;
#pragma unroll
    for (int p = 0; p < 4; p++) {
        int idx = p * 256 + tid;
        int r = idx >> 4, c4 = (idx & 15) * 4;
        float4 v = *(const float4*)(F + (size_t)(r0 + r) * D + d0 + c4);
        t[r][c4 + 0] = v.x; t[r][c4 + 1] = v.y; t[r][c4 + 2] = v.z; t[r][c4 + 3] = v.w;
    }
    __syncthreads();
#pragma unroll
    for (int p = 0; p < 2; p++) {
        int idx = p * 256 + tid;
        int d = idx >> 3, rc = (idx & 7) * 8;
        union { unsigned short s[8]; int4 v; } u;
#pragma unroll
        for (int j = 0; j < 8; j++) u.s[j] = f2bf(t[rc + j][d]);
        *(int4*)(FbT + (size_t)(d0 + d) * B + r0 + rc) = u.v;
    }
}

// -------- top-K on bf16 sim: moment-threshold + bisection + parallel rank select -----
__global__ __launch_bounds__(256) void k_topk2(const unsigned short* __restrict__ S,
                                               int* __restrict__ topk, int r0) {
    __shared__ float fs[4], fs2[4];
    __shared__ int cslot[2][4];
    __shared__ int islot[4];
    __shared__ unsigned long long buf[128];
    __shared__ int ccount;
    int li = blockIdx.x, tid = threadIdx.x;
    int i = r0 + li;
    const unsigned short* rp = S + (size_t)li * B;

    unsigned int key[32];
    float sum = 0.0f, sumsq = 0.0f;
#pragma unroll
    for (int j16 = 0; j16 < 4; j16++) {
        int4 v = *(const int4*)(rp + j16 * 2048 + tid * 8);
        const unsigned short* s8 = (const unsigned short*)&v;
#pragma unroll
        for (int q = 0; q < 8; q++) {
            int col = j16 * 2048 + tid * 8 + q;
            bool self = (col == i);
            unsigned int bits = ((unsigned int)s8[q]) << 16;
            float vv = self ? 0.0f : __builtin_bit_cast(float, bits);
            sum += vv;
            sumsq += vv * vv;
            unsigned int k = bits ^ ((bits & 0x80000000u) ? 0xFFFFFFFFu : 0x80000000u);
            key[j16 * 8 + q] = self ? 0u : k;
        }
    }

    float s1 = waveReduceSum(sum);
    float s2 = waveReduceSum(sumsq);
    int lane = tid & 63, wv = tid >> 6;
    if (lane == 0) { fs[wv] = s1; fs2[wv] = s2; }
    if (tid == 0) ccount = 0;
    __syncthreads();
    float S1 = fs[0] + fs[1] + fs[2] + fs[3];
    float S2 = fs2[0] + fs2[1] + fs2[2] + fs2[3];
    float mu = S1 * (1.0f / 8192.0f);
    float var = fmaxf(S2 * (1.0f / 8192.0f) - mu * mu, 0.0f);
    float sg = sqrtf(var);

    unsigned int klo = 0u, khi = 0xFFFFFFFFu;
    unsigned int T = 0;
    bool found = false;
    float z = 2.4f;
    for (int it = 0; it < 48; ++it) {
        unsigned int kt;
        if (it < 8) {
            float tf = mu + z * sg;
            unsigned int u = __builtin_bit_cast(unsigned int, tf);
            kt = u ^ ((u & 0x80000000u) ? 0xFFFFFFFFu : 0x80000000u);
            if (kt <= klo || kt >= khi) kt = klo + ((khi - klo) >> 1);
        } else {
            kt = klo + ((khi - klo) >> 1);
        }
        if (kt == klo) break;
        int c = 0;
#pragma unroll
        for (int j = 0; j < 32; j++) c += (key[j] > kt) ? 1 : 0;
        c = waveReduceSumI(c);
        if (lane == 0) cslot[it & 1][wv] = c;
        __syncthreads();
        int tot = cslot[it & 1][0] + cslot[it & 1][1] + cslot[it & 1][2] + cslot[it & 1][3];
        if (tot >= KNN && tot <= 128) { T = kt; found = true; break; }
        if (tot < KNN) { khi = kt; z -= 0.3f; }
        else          { klo = kt; z += 0.3f; }
    }
    if (!found) T = khi;
    __syncthreads();

#pragma unroll
    for (int j16 = 0; j16 < 4; j16++) {
#pragma unroll
        for (int q = 0; q < 8; q++) {
            int j = j16 * 8 + q;
            if (key[j] > T) {
                int p = atomicAdd(&ccount, 1);
                if (p < 128) {
                    int col = j16 * 2048 + tid * 8 + q;
                    buf[p] = ((unsigned long long)key[j] << 13) |
                             (unsigned long long)(8191 - col);
                }
            }
        }
    }
    __syncthreads();
    int C = ccount < 128 ? ccount : 128;

    if (tid < C) {
        unsigned long long my = buf[tid];
        int rank = 0;
        for (int j = 0; j < C; j++) rank += (buf[j] > my) ? 1 : 0;
        if (rank < KNN) topk[(size_t)i * KNN + rank] = 8191 - (int)(my & 0x1FFFull);
    }
    __syncthreads();

    if (C < KNN) {
        int last = -1;
        for (int it = C; it < KNN; ++it) {
            int best = 0x7fffffff;
#pragma unroll
            for (int j16 = 0; j16 < 4; j16++) {
#pragma unroll
                for (int q = 0; q < 8; q++) {
                    int j = j16 * 8 + q;
                    int col = j16 * 2048 + tid * 8 + q;
                    if (key[j] == T && col > last && col < best) best = col;
                }
            }
#pragma unroll
            for (int off = 32; off; off >>= 1) {
                int o = __shfl_down(best, off);
                best = (o < best) ? o : best;
            }
            if ((tid & 63) == 0) islot[tid >> 6] = best;
            __syncthreads();
            best = min(min(islot[0], islot[1]), min(islot[2], islot[3]));
            if (tid == 0) topk[(size_t)i * KNN + it] = best;
            last = best;
            __syncthreads();
        }
    }
}

// ---------------- graph build ----------------
__global__ void k_zero2(int* __restrict__ a, int* __restrict__ b) {
    int i = blockIdx.x * 256 + threadIdx.x;
    a[i] = 0;
    b[i] = 0;
}

__global__ void k_count(const int* __restrict__ topk, int* __restrict__ indeg) {
    int e = blockIdx.x * 256 + threadIdx.x;
    atomicAdd(&indeg[topk[e]], 1);
}

__global__ __launch_bounds__(1024) void k_scan(const int* __restrict__ indeg,
                                               int* __restrict__ roff) {
    __shared__ int sums[1024];
    int tid = threadIdx.x;
    int base = tid * 8;
    int loc[8];
    int s = 0;
#pragma unroll
    for (int j = 0; j < 8; j++) { loc[j] = s; s += indeg[base + j]; }
    sums[tid] = s;
    __syncthreads();
    for (int off = 1; off < 1024; off <<= 1) {
        int v = (tid >= off) ? sums[tid - off] : 0;
        __syncthreads();
        sums[tid] += v;
        __syncthreads();
    }
    int prev = (tid > 0) ? sums[tid - 1] : 0;
#pragma unroll
    for (int j = 0; j < 8; j++) roff[base + j] = prev + loc[j];
    if (tid == 1023) roff[B] = sums[1023];
}

// dinv + fused gather weight wf = dinv * fscale
__global__ void k_dinv(const int* __restrict__ indeg, const float* __restrict__ fscale,
                       float* __restrict__ dinv, float* __restrict__ wf) {
    int i = blockIdx.x * 256 + threadIdx.x;
    float dg = (float)(KNN + indeg[i]);
    float dv = fminf(1.0f / sqrtf(dg), 1e6f);
    dinv[i] = dv;
    wf[i] = dv * fscale[i];
}

__global__ void k_fill(const int* __restrict__ topk, const int* __restrict__ roff,
                       int* __restrict__ fill, int* __restrict__ ridx) {
    int e = blockIdx.x * 256 + threadIdx.x;
    int dst = topk[e];
    int src = e >> 5;
    int pos = atomicAdd(&fill[dst], 1);
    ridx[roff[dst] + pos] = src;
}

// ------- SpMM 1: gathers int8 Fq (4 MB, L2-resident); fused weights wf -------
__global__ __launch_bounds__(128) void k_spmm1(const unsigned int* __restrict__ Fq,
                                               const float* __restrict__ wf,
                                               unsigned int* __restrict__ G1q,
                                               float* __restrict__ wg,
                                               const int* __restrict__ topk,
                                               const int* __restrict__ roff,
                                               const int* __restrict__ ridx,
                                               const float* __restrict__ dinv) {
    int i = blockIdx.x, tid = threadIdx.x;
    float a0 = 0, a1 = 0, a2 = 0, a3 = 0;
    const int* ti = topk + (size_t)i * KNN;
#pragma unroll
    for (int k8 = 0; k8 < KNN / 8; k8++) {
        int4 na = *(const int4*)(ti + k8 * 8);
        int4 nb = *(const int4*)(ti + k8 * 8 + 4);
        unsigned int q0 = Fq[(size_t)na.x * GROW + tid];
        unsigned int q1 = Fq[(size_t)na.y * GROW + tid];
        unsigned int q2 = Fq[(size_t)na.z * GROW + tid];
        unsigned int q3 = Fq[(size_t)na.w * GROW + tid];
        unsigned int q4 = Fq[(size_t)nb.x * GROW + tid];
        unsigned int q5 = Fq[(size_t)nb.y * GROW + tid];
        unsigned int q6 = Fq[(size_t)nb.z * GROW + tid];
        unsigned int q7 = Fq[(size_t)nb.w * GROW + tid];
        float w0 = wf[na.x], w1 = wf[na.y], w2 = wf[na.z], w3 = wf[na.w];
        float w4 = wf[nb.x], w5 = wf[nb.y], w6 = wf[nb.z], w7 = wf[nb.w];
        float4 p0 = qdec(q0), p1 = qdec(q1), p2 = qdec(q2), p3 = qdec(q3);
        float4 p4 = qdec(q4), p5 = qdec(q5), p6 = qdec(q6), p7 = qdec(q7);
        a0 += w0 * p0.x + w1 * p1.x + w2 * p2.x + w3 * p3.x +
              w4 * p4.x + w5 * p5.x + w6 * p6.x + w7 * p7.x;
        a1 += w0 * p0.y + w1 * p1.y + w2 * p2.y + w3 * p3.y +
              w4 * p4.y + w5 * p5.y + w6 * p6.y + w7 * p7.y;
        a2 += w0 * p0.z + w1 * p1.z + w2 * p2.z + w3 * p3.z +
              w4 * p4.z + w5 * p5.z + w6 * p6.z + w7 * p7.z;
        a3 += w0 * p0.w + w1 * p1.w + w2 * p2.w + w3 * p3.w +
              w4 * p4.w + w5 * p5.w + w6 * p6.w + w7 * p7.w;
    }
    int s = roff[i], e = roff[i + 1];
    int t = s;
    for (; t + 2 <= e; t += 2) {
        int j0 = ridx[t], j1 = ridx[t + 1];
        float w0 = wf[j0], w1 = wf[j1];
        float4 p0 = qdec(Fq[(size_t)j0 * GROW + tid]);
        float4 p1 = qdec(Fq[(size_t)j1 * GROW + tid]);
        a0 += w0 * p0.x + w1 * p1.x;
        a1 += w0 * p0.y + w1 * p1.y;
        a2 += w0 * p0.z + w1 * p1.z;
        a3 += w0 * p0.w + w1 * p1.w;
    }
    if (t < e) {
        int j0 = ridx[t];
        float w0 = wf[j0];
        float4 p0 = qdec(Fq[(size_t)j0 * GROW + tid]);
        a0 += w0 * p0.x; a1 += w0 * p0.y; a2 += w0 * p0.z; a3 += w0 * p0.w;
    }
    float wi = dinv[i];
    float g0 = wi * a0, g1 = wi * a1, g2 = wi * a2, g3 = wi * a3;

    float am = fmaxf(fmaxf(fabsf(g0), fabsf(g1)), fmaxf(fabsf(g2), fabsf(g3)));
    am = waveReduceMax(am);
    __shared__ float rm[2];
    if ((tid & 63) == 0) rm[tid >> 6] = am;
    __syncthreads();
    float amax = fmaxf(rm[0], rm[1]);
    if (tid == 0) wg[i] = wi * amax * (1.0f / 127.0f);  // dinv*gscale fused
    float se = (amax > 0.0f) ? 127.0f / amax : 0.0f;
    G1q[(size_t)i * GROW + tid] = qenc(g0, g1, g2, g3, se);
}

// ------- SpMM 2 fused with Yb build: gathers int8 G1q; fused weights wg -------
__global__ __launch_bounds__(128) void k_spmm2y(const unsigned int* __restrict__ G1q,
                                                const float* __restrict__ wg,
                                                const float* __restrict__ F,
                                                const float* __restrict__ invnf,
                                                unsigned short* __restrict__ Yb,
                                                const int* __restrict__ topk,
                                                const int* __restrict__ roff,
                                                const int* __restrict__ ridx,
                                                const float* __restrict__ dinv) {
    int i = blockIdx.x, tid = threadIdx.x;
    float a0 = 0, a1 = 0, a2 = 0, a3 = 0;
    const int* ti = topk + (size_t)i * KNN;
#pragma unroll
    for (int k8 = 0; k8 < KNN / 8; k8++) {
        int4 na = *(const int4*)(ti + k8 * 8);
        int4 nb = *(const int4*)(ti + k8 * 8 + 4);
        unsigned int q0 = G1q[(size_t)na.x * GROW + tid];
        unsigned int q1 = G1q[(size_t)na.y * GROW + tid];
        unsigned int q2 = G1q[(size_t)na.z * GROW + tid];
        unsigned int q3 = G1q[(size_t)na.w * GROW + tid];
        unsigned int q4 = G1q[(size_t)nb.x * GROW + tid];
        unsigned int q5 = G1q[(size_t)nb.y * GROW + tid];
        unsigned int q6 = G1q[(size_t)nb.z * GROW + tid];
        unsigned int q7 = G1q[(size_t)nb.w * GROW + tid];
        float w0 = wg[na.x], w1 = wg[na.y], w2 = wg[na.z], w3 = wg[na.w];
        float w4 = wg[nb.x], w5 = wg[nb.y], w6 = wg[nb.z], w7 = wg[nb.w];
        float4 p0 = qdec(q0), p1 = qdec(q1), p2 = qdec(q2), p3 = qdec(q3);
        float4 p4 = qdec(q4), p5 = qdec(q5), p6 = qdec(q6), p7 = qdec(q7);
        a0 += w0 * p0.x + w1 * p1.x + w2 * p2.x + w3 * p3.x +
              w4 * p4.x + w5 * p5.x + w6 * p6.x + w7 * p7.x;
        a1 += w0 * p0.y + w1 * p1.y + w2 * p2.y + w3 * p3.y +
              w4 * p4.y + w5 * p5.y + w6 * p6.y + w7 * p7.y;
        a2 += w0 * p0.z + w1 * p1.z + w2 * p2.z + w3 * p3.z +
              w4 * p4.z + w5 * p5.z + w6 * p6.z + w7 * p7.z;
        a3 += w0 * p0.w + w1 * p1.w + w2 * p2.w + w3 * p3.w +
              w4 * p4.w + w5 * p5.w + w6 * p6.w + w7 * p7.w;
    }
    int s = roff[i], e = roff[i + 1];
    int t = s;
    for (; t + 2 <= e; t += 2) {
        int j0 = ridx[t], j1 = ridx[t + 1];
        float w0 = wg[j0], w1 = wg[j1];
        float4 p0 = qdec(G1q[(size_t)j0 * GROW + tid]);
        float4 p1 = qdec(G1q[(size_t)j1 * GROW + tid]);
        a0 += w0 * p0.x + w1 * p1.x;
        a1 += w0 * p0.y + w1 * p1.y;
        a2 += w0 * p0.z + w1 * p1.z;
        a3 += w0 * p0.w + w1 * p1.w;
    }
    if (t < e) {
        int j0 = ridx[t];
        float w0 = wg[j0];
        float4 p0 = qdec(G1q[(size_t)j0 * GROW + tid]);
        a0 += w0 * p0.x; a1 += w0 * p0.y; a2 += w0 * p0.z; a3 += w0 * p0.w;
    }
    float wi = dinv[i];
    float g0 = wi * a0, g1 = wi * a1, g2 = wi * a2, g3 = wi * a3;

    float ss = g0 * g0 + g1 * g1 + g2 * g2 + g3 * g3;
    ss = waveReduceSum(ss);
    __shared__ float s2[2];
    if ((tid & 63) == 0) s2[tid >> 6] = ss;
    __syncthreads();
    float invng = 1.0f / fmaxf(sqrtf(s2[0] + s2[1]), 1e-12f);

    float4 f = ((const float4*)(F + (size_t)i * D))[tid];
    float inf_ = 10.0f * invnf[i];
    union { unsigned short s4[4]; int2 q; } u;
    u.s4[0] = f2bf(f.x * inf_ + g0 * invng);
    u.s4[1] = f2bf(f.y * inf_ + g1 * invng);
    u.s4[2] = f2bf(f.z * inf_ + g2 * invng);
    u.s4[3] = f2bf(f.w * inf_ + g3 * invng);
    *(int2*)(Yb + (size_t)i * D + tid * 4) = u.q;
}

// ------- register-resident online row softmax: fp16 logits in, bf16 weights out -----
__global__ __launch_bounds__(256) void k_softmax(unsigned short* __restrict__ chunk16,
                                                 int rowstride) {
    __shared__ float sm[4], sl[4];
    int li = blockIdx.x, tid = threadIdx.x;
    unsigned short* rp = chunk16 + (size_t)li * rowstride;
    float v[32];
    float mt = -FLT_MAX;
#pragma unroll
    for (int j16 = 0; j16 < 4; j16++) {
        int4 w = *(const int4*)(rp + j16 * 2048 + tid * 8);
        const unsigned short* s8 = (const unsigned short*)&w;
#pragma unroll
        for (int q = 0; q < 8; q++) {
            float f = h2f(s8[q]);
            v[j16 * 8 + q] = f;
            mt = fmaxf(mt, f);
        }
    }
    float l = 0.0f;
#pragma unroll
    for (int j = 0; j < 32; j++) {
        v[j] = __expf(v[j] - mt);
        l += v[j];
    }
    float m = mt, lw = l;
#pragma unroll
    for (int off = 32; off; off >>= 1) {
        float om = __shfl_down(m, off);
        float ol = __shfl_down(lw, off);
        float nm = fmaxf(m, om);
        lw = lw * __expf(m - nm) + ol * __expf(om - nm);
        m = nm;
    }
    if ((tid & 63) == 0) { sm[tid >> 6] = m; sl[tid >> 6] = lw; }
    __syncthreads();
    float M = fmaxf(fmaxf(sm[0], sm[1]), fmaxf(sm[2], sm[3]));
    float L = sl[0] * __expf(sm[0] - M) + sl[1] * __expf(sm[1] - M) +
              sl[2] * __expf(sm[2] - M) + sl[3] * __expf(sm[3] - M);
    float fct = __expf(mt - M) / L;
#pragma unroll
    for (int j16 = 0; j16 < 4; j16++) {
        union { unsigned short s[8]; int4 w; } u;
#pragma unroll
        for (int q = 0; q < 8; q++) u.s[q] = f2bf(v[j16 * 8 + q] * fct);
        *(int4*)(rp + j16 * 2048 + tid * 8) = u.w;
    }
}

extern "C" void kernel_launch(void* const* d_in, const int* in_sizes, int n_in,
                              void* d_out, int out_size, void* d_ws, size_t ws_size,
                              hipStream_t stream) {
    (void)in_sizes; (void)n_in; (void)out_size;
    const float* F = (const float*)d_in[0];
    float* out = (float*)d_out;

    char* ws = (char*)d_ws;
    size_t off = 0;
    auto take = [&](size_t bytes) -> void* {
        void* p = ws + off;
        off += (bytes + 255) & ~(size_t)255;
        return p;
    };
    float* invnf = (float*)take((size_t)B * 4);
    float* dinv = (float*)take((size_t)B * 4);
    float* fscale = (float*)take((size_t)B * 4);
    float* wf = (float*)take((size_t)B * 4);
    float* wg = (float*)take((size_t)B * 4);
    int* topk = (int*)take((size_t)B * KNN * 4);
    int* indeg = (int*)take((size_t)B * 4);
    int* roff = (int*)take((size_t)(B + 1) * 4);
    int* rfill = (int*)take((size_t)B * 4);
    int* ridx = (int*)take((size_t)B * KNN * 4);
    unsigned short* Xb = (unsigned short*)take((size_t)B * D * 2);
    unsigned int* Fq = (unsigned int*)take((size_t)B * GROW * 4);
    unsigned short* Yb = (unsigned short*)take((size_t)B * D * 2);
    unsigned short* FbT = (unsigned short*)take((size_t)D * B * 2);
    size_t fixed = off;

    int R = 4096;  // larger chunks = fewer serialized phases; auto-shrinks to fit ws
    if (ws_size > 0) {
        while (R > 128 && fixed + (size_t)R * B * 4 > ws_size) R >>= 1;
    } else {
        R = 1024;
    }
    float* chunk = (float*)(ws + fixed);
    unsigned int* G1q = (unsigned int*)out;  // d_out scratch: 4 MB of 16

    // split-K: fp16 partials in the upper 16 KB of each 32 KB chunk row ->
    // SK*D*2B <= 16 KB -> SK <= 16. SK=16: 2048 blocks (8/CU) for latency hiding.
    int SK = 16;
    int ksplit = B / SK;
    bool use8 = (R % 256) == 0;

    // 1. Xb / Fq / fscale / invnf; FbT = bf16 F^T
    k_norm<<<B, 128, 0, stream>>>(F, Xb, Fq, fscale, invnf);
    dim3 gt(B / 64, D / 64);
    k_transpose<<<gt, 256, 0, stream>>>(F, FbT);

    // 2. chunked: sim = Xb Xb^T (bf16 out) + top-K on bf16
    for (int r0 = 0; r0 < B; r0 += R) {
        if (use8) {
            dim3 g8(B / 256, R / 256);
            k_mfma8<1><<<g8, 512, 0, stream>>>(Xb + (size_t)r0 * D, D, Xb, D, chunk, B, D);
        } else {
            dim3 g(B / 128, R / 128);
            k_mfma_nt<1><<<g, 256, 0, stream>>>(Xb + (size_t)r0 * D, D, Xb, D, chunk, B, 0, D);
        }
        k_topk2<<<R, 256, 0, stream>>>((const unsigned short*)chunk, topk, r0);
    }

    // 3. graph build
    k_zero2<<<B / 256, 256, 0, stream>>>(indeg, rfill);
    k_count<<<B * KNN / 256, 256, 0, stream>>>(topk, indeg);
    k_scan<<<1, 1024, 0, stream>>>(indeg, roff);
    k_dinv<<<B / 256, 256, 0, stream>>>(indeg, fscale, dinv, wf);
    k_fill<<<B * KNN / 256, 256, 0, stream>>>(topk, roff, rfill, ridx);

    // 4. G1q = A_hat Fq (int8 tables, L2-resident); Yb = 10*Xhat + normalize(A_hat G1q)
    k_spmm1<<<B, 128, 0, stream>>>(Fq, wf, G1q, wg, topk, roff, ridx, dinv);
    k_spmm2y<<<B, 128, 0, stream>>>(G1q, wg, F, invnf, Yb, topk, roff, ridx, dinv);

    // 5. chunked: logits = Xb @ Yb^T (fp16 out, first 16KB of each 32KB row)
    //    -> softmax (fp16 in, bf16 weights in place)
    //    -> split-K final GEMM with fp16 partials (upper 16KB) -> fp32 reduce
    for (int r0 = 0; r0 < B; r0 += R) {
        if (use8) {
            dim3 g8(B / 256, R / 256);
            k_mfma8<2><<<g8, 512, 0, stream>>>(Xb + (size_t)r0 * D, D, Yb, D, chunk,
                                               2 * B, D);
        } else {
            dim3 g(B / 128, R / 128);
            k_mfma_nt<2><<<g, 256, 0, stream>>>(Xb + (size_t)r0 * D, D, Yb, D, chunk,
                                                2 * B, 0, D);
        }
        k_softmax<<<R, 256, 0, stream>>>((unsigned short*)chunk, 2 * B);
        unsigned short* part16 = (unsigned short*)chunk + 8192;  // upper 16KB of rows
        dim3 gf(D / 128, R / 128, SK);
        k_mfma_nt<2><<<gf, 256, 0, stream>>>((const unsigned short*)chunk, 2 * B, FbT, B,
                                             part16, 2 * B, D, ksplit);
        k_redh<<<R / 2, 256, 0, stream>>>(part16, out + (size_t)r0 * D, SK);
    }
}

// Round 22
// 478.606 us; speedup vs baseline: 1.0292x; 1.0292x over previous
//
#include <hip/hip_runtime.h>
#include <hip/hip_bf16.h>
#include <float.h>
#include <math.h>

constexpr int B = 8192;
constexpr int D = 512;
constexpr int KNN = 32;
constexpr int GROW = D / 4;  // packed int8x4 words per row

typedef __attribute__((ext_vector_type(8))) short bhalf8;
typedef __attribute__((ext_vector_type(4))) float floatx4;

#if defined(__has_builtin)
#if __has_builtin(__builtin_amdgcn_global_load_lds)
#define HAS_GLD 1
#else
#define HAS_GLD 0
#endif
#else
#define HAS_GLD 0
#endif

__device__ __forceinline__ unsigned short f2bf(float f) {
    __hip_bfloat16 h = __float2bfloat16(f);
    return __builtin_bit_cast(unsigned short, h);
}

__device__ __forceinline__ float bf2f(unsigned short u) {
    unsigned int x = ((unsigned int)u) << 16;
    return __builtin_bit_cast(float, x);
}

__device__ __forceinline__ unsigned short f2h(float f) {
    _Float16 h = (_Float16)f;
    return __builtin_bit_cast(unsigned short, h);
}

__device__ __forceinline__ float h2f(unsigned short u) {
    _Float16 h = __builtin_bit_cast(_Float16, u);
    return (float)h;
}

__device__ __forceinline__ float waveReduceSum(float v) {
#pragma unroll
    for (int off = 32; off; off >>= 1) v += __shfl_down(v, off);
    return v;
}

__device__ __forceinline__ float waveReduceMax(float v) {
#pragma unroll
    for (int off = 32; off; off >>= 1) v = fmaxf(v, __shfl_down(v, off));
    return v;
}

__device__ __forceinline__ int waveReduceSumI(int v) {
#pragma unroll
    for (int off = 32; off; off >>= 1) v += __shfl_down(v, off);
    return v;
}

// decode packed int8x4 -> float4 (linear quant; scale folded into gather weight)
__device__ __forceinline__ float4 qdec(unsigned int w) {
    float4 r;
    r.x = (float)((int)(w << 24) >> 24);
    r.y = (float)((int)(w << 16) >> 24);
    r.z = (float)((int)(w << 8) >> 24);
    r.w = (float)((int)w >> 24);
    return r;
}

__device__ __forceinline__ unsigned int qenc(float a, float b, float c, float d, float se) {
    int qx = (int)rintf(a * se); qx = max(-127, min(127, qx));
    int qy = (int)rintf(b * se); qy = max(-127, min(127, qy));
    int qz = (int)rintf(c * se); qz = max(-127, min(127, qz));
    int qw = (int)rintf(d * se); qw = max(-127, min(127, qw));
    return (unsigned int)(qx & 0xff) | ((unsigned int)(qy & 0xff) << 8) |
           ((unsigned int)(qz & 0xff) << 16) | ((unsigned int)(qw & 0xff) << 24);
}

// stage one 16B chunk of a 128x32-bf16 tile (linear LDS, 64B rows). (128^2 kernel)
__device__ __forceinline__ void stage_chunk(const unsigned short* __restrict__ g,
                                            char* __restrict__ lds_tile, int c) {
#if HAS_GLD
    char* wavebase = lds_tile + (size_t)(c & ~63) * 16;
    __builtin_amdgcn_global_load_lds((const __attribute__((address_space(1))) void*)g,
                                     (__attribute__((address_space(3))) void*)wavebase,
                                     16, 0, 0);
#else
    *(int4*)(lds_tile + (size_t)c * 16) = *(const int4*)g;
#endif
}

// C-write helper: OUTMODE 0=fp32, 1=bf16, 2=fp16. ldc in elements of the out type.
template <int OUTMODE>
__device__ __forceinline__ void cwrite(void* Cv, size_t idx, float v) {
    if (OUTMODE == 0) ((float*)Cv)[idx] = v;
    else if (OUTMODE == 1) ((unsigned short*)Cv)[idx] = f2bf(v);
    else ((unsigned short*)Cv)[idx] = f2h(v);
}

// ================= 8-phase 256x256 bf16 NT GEMM (m201-style) =================
template <int OUTMODE>
__global__ __launch_bounds__(512) void k_mfma8(
    const unsigned short* __restrict__ A, int lda,
    const unsigned short* __restrict__ Bm, int ldb,
    void* __restrict__ Cv, int ldc, int Kd) {
    __shared__ __align__(16) char lds[131072];
    constexpr int AOFF0 = 0, AOFF1 = 32768, BOFF0 = 65536, BOFF1 = 98304;

    int tid = threadIdx.x;
    int lane = tid & 63;
    int wid = tid >> 6;
    int wm = (wid >> 2) * 128;
    int wn = (wid & 3) * 64;
    int lrow = lane & 15;
    int khi = lane >> 4;
    int lk7 = lane & 7;
    int gm = blockIdx.y * 256, gn = blockIdx.x * 256;

    floatx4 zero4 = {0.0f, 0.0f, 0.0f, 0.0f};
    floatx4 acc[8][4];
#pragma unroll
    for (int m = 0; m < 8; m++)
#pragma unroll
        for (int n = 0; n < 4; n++) acc[m][n] = zero4;
    bhalf8 bfrag[4][2];

    auto stage_half = [&](const unsigned short* __restrict__ src, int ld,
                          int rowg0, int k0, int ldsbase) {
#pragma unroll
        for (int rd = 0; rd < 2; rd++) {
            int idx = rd * 512 + tid;
            int r = idx >> 3;
            int s = (idx & 7) ^ (r & 7);
            const unsigned short* g = src + (size_t)(rowg0 + r) * ld + k0 + s * 8;
#if HAS_GLD
            char* wb = lds + ldsbase + rd * 8192 + (tid >> 6) * 1024;
            __builtin_amdgcn_global_load_lds(
                (const __attribute__((address_space(1))) void*)g,
                (__attribute__((address_space(3))) void*)wb, 16, 0, 0);
#else
            *(int4*)(lds + ldsbase + (size_t)idx * 16) = *(const int4*)g;
#endif
        }
    };
    auto rdA = [&](int bufoff, int mf, int kk) -> bhalf8 {
        int r = wm + mf * 16 + lrow;
        int slot = ((kk << 2) + khi) ^ lk7;
        return *(const bhalf8*)(lds + bufoff + r * 128 + slot * 16);
    };
    auto rdB = [&](int bufoff, int nf, int kk) -> bhalf8 {
        int r = wn + nf * 16 + lrow;
        int slot = ((kk << 2) + khi) ^ lk7;
        return *(const bhalf8*)(lds + bufoff + r * 128 + slot * 16);
    };

    stage_half(A, lda, gm, 0, AOFF0);
    stage_half(A, lda, gm + 128, 0, AOFF0 + 16384);
    stage_half(Bm, ldb, gn, 0, BOFF0);
    stage_half(Bm, ldb, gn + 128, 0, BOFF0 + 16384);
    stage_half(Bm, ldb, gn, 64, BOFF1);
    stage_half(Bm, ldb, gn + 128, 64, BOFF1 + 16384);
    asm volatile("s_waitcnt vmcnt(4)" ::: "memory");
    __builtin_amdgcn_s_barrier();

#define PH(mq, AO, BO, STAGE_STMT, TAIL_STMT)                                      \
    {                                                                              \
        if ((mq) == 0) {                                                           \
            _Pragma("unroll") for (int nf = 0; nf < 4; nf++) {                     \
                bfrag[nf][0] = rdB((BO), nf, 0);                                   \
                bfrag[nf][1] = rdB((BO), nf, 1);                                   \
            }                                                                      \
        }                                                                          \
        bhalf8 a00 = rdA((AO), 2 * (mq), 0);                                       \
        bhalf8 a01 = rdA((AO), 2 * (mq), 1);                                       \
        bhalf8 a10 = rdA((AO), 2 * (mq) + 1, 0);                                   \
        bhalf8 a11 = rdA((AO), 2 * (mq) + 1, 1);                                   \
        STAGE_STMT;                                                                \
        __builtin_amdgcn_s_barrier();                                              \
        asm volatile("s_waitcnt lgkmcnt(0)" ::: "memory");                         \
        __builtin_amdgcn_sched_barrier(0);                                         \
        __builtin_amdgcn_s_setprio(1);                                             \
        _Pragma("unroll") for (int nf = 0; nf < 4; nf++) {                         \
            acc[2 * (mq)][nf] = __builtin_amdgcn_mfma_f32_16x16x32_bf16(           \
                a00, bfrag[nf][0], acc[2 * (mq)][nf], 0, 0, 0);                    \
            acc[2 * (mq) + 1][nf] = __builtin_amdgcn_mfma_f32_16x16x32_bf16(       \
                a10, bfrag[nf][0], acc[2 * (mq) + 1][nf], 0, 0, 0);                \
        }                                                                          \
        _Pragma("unroll") for (int nf = 0; nf < 4; nf++) {                         \
            acc[2 * (mq)][nf] = __builtin_amdgcn_mfma_f32_16x16x32_bf16(           \
                a01, bfrag[nf][1], acc[2 * (mq)][nf], 0, 0, 0);                    \
            acc[2 * (mq) + 1][nf] = __builtin_amdgcn_mfma_f32_16x16x32_bf16(       \
                a11, bfrag[nf][1], acc[2 * (mq) + 1][nf], 0, 0, 0);                \
        }                                                                          \
        __builtin_amdgcn_s_setprio(0);                                             \
        TAIL_STMT;                                                                 \
        __builtin_amdgcn_s_barrier();                                              \
    }

    int iters = Kd >> 7;
    for (int it = 0; it < iters; ++it) {
        bool lastI = (it == iters - 1);
        int kodd = (2 * it + 1) << 6;
        int kne = (2 * it + 2) << 6;
        int kno = (2 * it + 3) << 6;
        PH(0, AOFF0, BOFF0, stage_half(A, lda, gm, kodd, AOFF1), );
        PH(1, AOFF0, BOFF0, stage_half(A, lda, gm + 128, kodd, AOFF1 + 16384), );
        PH(2, AOFF0, BOFF0, if (!lastI) stage_half(Bm, ldb, gn, kne, BOFF0), );
        PH(3, AOFF0, BOFF0, if (!lastI) stage_half(Bm, ldb, gn + 128, kne, BOFF0 + 16384),
           if (lastI) { asm volatile("s_waitcnt vmcnt(0)" ::: "memory"); } else {
               asm volatile("s_waitcnt vmcnt(4)" ::: "memory"); });
        PH(0, AOFF1, BOFF1, if (!lastI) stage_half(A, lda, gm, kne, AOFF0), );
        PH(1, AOFF1, BOFF1, if (!lastI) stage_half(A, lda, gm + 128, kne, AOFF0 + 16384), );
        PH(2, AOFF1, BOFF1, if (!lastI) stage_half(Bm, ldb, gn, kno, BOFF1), );
        PH(3, AOFF1, BOFF1, if (!lastI) stage_half(Bm, ldb, gn + 128, kno, BOFF1 + 16384),
           if (lastI) { asm volatile("s_waitcnt vmcnt(0)" ::: "memory"); } else {
               asm volatile("s_waitcnt vmcnt(4)" ::: "memory"); });
    }
#undef PH

#pragma unroll
    for (int mf = 0; mf < 8; mf++) {
#pragma unroll
        for (int nf = 0; nf < 4; nf++) {
            int cc = gn + wn + nf * 16 + lrow;
#pragma unroll
            for (int q = 0; q < 4; q++) {
                int r = gm + wm + mf * 16 + khi * 4 + q;
                cwrite<OUTMODE>(Cv, (size_t)r * ldc + cc, acc[mf][nf][q]);
            }
        }
    }
}

// ---------------- bf16 MFMA GEMM, NT form (128^2; final GEMM + fallback) ----------
// For the split-K config (gridDim = {4, ny, nz>=8}), remap blocks so the 4 x-blocks
// sharing an A-panel (same y,z) land on the SAME XCD (lid mod 8 constant).
// Bijective: lid = (g%8) + 8*((g/8)*4 + bx), g = bz*ny + by  (requires ny*nz % 8 == 0).
template <int OUTMODE>
__global__ __launch_bounds__(256, 2) void k_mfma_nt(
    const unsigned short* __restrict__ A, int lda,
    const unsigned short* __restrict__ B1, int ldb,
    void* __restrict__ Cv, int ldc, int zstride, int ksplit) {
    __shared__ __align__(16) char smem[2 * 8192];
    char* Asm = smem;
    char* B1sm = smem + 8192;

    int tid = threadIdx.x;
    int lane = tid & 63;
    int wid = tid >> 6;
    int wm = (wid >> 1) * 64, wn = (wid & 1) * 64;
    int lrow = lane & 15;
    int kh = lane >> 4;

    int bx = blockIdx.x, by = blockIdx.y, bz = blockIdx.z;
    int ny = gridDim.y;
    if (gridDim.x == 4 && gridDim.z >= 8 && ((ny * gridDim.z) & 7) == 0) {
        int lid = bx + 4 * (by + ny * bz);  // hw dispatch linear id (x fastest)
        int xcd = lid & 7;
        int h = lid >> 3;
        bx = h & 3;
        int g = (h >> 2) * 8 + xcd;  // group = A-panel key
        by = g % ny;
        bz = g / ny;
    }
    int gm = by * 128, gn = bx * 128;
    int kbeg = bz * ksplit;
    size_t zoff = (size_t)bz * zstride;

    floatx4 zero4 = {0.0f, 0.0f, 0.0f, 0.0f};
    floatx4 acc1[4][4];
#pragma unroll
    for (int m = 0; m < 4; m++)
#pragma unroll
        for (int n = 0; n < 4; n++) acc1[m][n] = zero4;

    for (int k0 = kbeg; k0 < kbeg + ksplit; k0 += 32) {
        __syncthreads();
#pragma unroll
        for (int p = 0; p < 2; p++) {
            int c = p * 256 + tid;
            int row = c >> 2;
            int col = (c & 3) * 8;
            stage_chunk(A + (size_t)(gm + row) * lda + k0 + col, Asm, c);
            stage_chunk(B1 + (size_t)(gn + row) * ldb + k0 + col, B1sm, c);
        }
        __syncthreads();

        bhalf8 a[4];
#pragma unroll
        for (int m = 0; m < 4; m++)
            a[m] = *(const bhalf8*)(Asm + (wm + m * 16 + lrow) * 64 + kh * 16);
#pragma unroll
        for (int n = 0; n < 4; n++) {
            bhalf8 b = *(const bhalf8*)(B1sm + (wn + n * 16 + lrow) * 64 + kh * 16);
#pragma unroll
            for (int m = 0; m < 4; m++)
                acc1[m][n] = __builtin_amdgcn_mfma_f32_16x16x32_bf16(a[m], b, acc1[m][n], 0, 0, 0);
        }
    }

#pragma unroll
    for (int m = 0; m < 4; m++) {
#pragma unroll
        for (int n = 0; n < 4; n++) {
            int cc = gn + wn + n * 16 + lrow;
#pragma unroll
            for (int q = 0; q < 4; q++) {
                int r = gm + wm + m * 16 + kh * 4 + q;
                cwrite<OUTMODE>(Cv, zoff + (size_t)r * ldc + cc, acc1[m][n][q]);
            }
        }
    }
}

// ---------------- split-K reduce over fp16 partials ----------------
// partial(z, lr, d) at P16 + lr*16384 + z*512 + d  (upper 16 KB of 32 KB chunk rows)
__global__ __launch_bounds__(256) void k_redh(const unsigned short* __restrict__ P16,
                                              float* __restrict__ outp, int SK) {
    int idx = blockIdx.x * 256 + threadIdx.x;
    int lr = idx >> 7;
    int d4 = (idx & 127) * 4;
    const unsigned short* base = P16 + (size_t)lr * 16384 + d4;
    float s0 = 0, s1 = 0, s2 = 0, s3 = 0;
    for (int p = 0; p < SK; p++) {
        int2 w = *(const int2*)(base + (size_t)p * 512);
        const unsigned short* h = (const unsigned short*)&w;
        s0 += h2f(h[0]); s1 += h2f(h[1]); s2 += h2f(h[2]); s3 += h2f(h[3]);
    }
    float4 o; o.x = s0; o.y = s1; o.z = s2; o.w = s3;
    *(float4*)(outp + (size_t)lr * 512 + d4) = o;
}

// ------- normalize rows of F -> bf16 Xb, int8 Fq + fscale, invnf -------
__global__ __launch_bounds__(128) void k_norm(const float* __restrict__ F,
                                              unsigned short* __restrict__ Xb,
                                              unsigned int* __restrict__ Fq,
                                              float* __restrict__ fscale,
                                              float* __restrict__ invnf) {
    int row = blockIdx.x, tid = threadIdx.x;
    float4 v = ((const float4*)(F + (size_t)row * D))[tid];
    float ss = v.x * v.x + v.y * v.y + v.z * v.z + v.w * v.w;
    float am = fmaxf(fmaxf(fabsf(v.x), fabsf(v.y)), fmaxf(fabsf(v.z), fabsf(v.w)));
    ss = waveReduceSum(ss);
    am = waveReduceMax(am);
    __shared__ float rs[2], rm[2];
    if ((tid & 63) == 0) { rs[tid >> 6] = ss; rm[tid >> 6] = am; }
    __syncthreads();
    float inv = 1.0f / fmaxf(sqrtf(rs[0] + rs[1]), 1e-12f);
    float amax = fmaxf(rm[0], rm[1]);
    if (tid == 0) { invnf[row] = inv; fscale[row] = amax * (1.0f / 127.0f); }
    union { unsigned short s[4]; int2 q; } ux;
    ux.s[0] = f2bf(v.x * inv); ux.s[1] = f2bf(v.y * inv);
    ux.s[2] = f2bf(v.z * inv); ux.s[3] = f2bf(v.w * inv);
    *(int2*)(Xb + (size_t)row * D + tid * 4) = ux.q;
    float se = (amax > 0.0f) ? 127.0f / amax : 0.0f;
    Fq[(size_t)row * GROW + tid] = qenc(v.x, v.y, v.z, v.w, se);
}

// ---------------- transpose F (fp32 BxD) -> FbT (bf16 DxB) ----------------
__global__ __launch_bounds__(256) void k_transpose(const float* __restrict__ F,
                                                   unsigned short* __restrict__ FbT) {
    __shared__ float t[64][65];
    int r0 = blockIdx.x * 64, d0 = blockIdx.y * 64;
    int tid = threadIdx.x;
#pragma unroll
    for (int p = 0; p < 4; p++) {
        int idx = p * 256 + tid;
        int r = idx >> 4, c4 = (idx & 15) * 4;
        float4 v = *(const float4*)(F + (size_t)(r0 + r) * D + d0 + c4);
        t[r][c4 + 0] = v.x; t[r][c4 + 1] = v.y; t[r][c4 + 2] = v.z; t[r][c4 + 3] = v.w;
    }
    __syncthreads();
#pragma unroll
    for (int p = 0; p < 2; p++) {
        int idx = p * 256 + tid;
        int d = idx >> 3, rc = (idx & 7) * 8;
        union { unsigned short s[8]; int4 v; } u;
#pragma unroll
        for (int j = 0; j < 8; j++) u.s[j] = f2bf(t[rc + j][d]);
        *(int4*)(FbT + (size_t)(d0 + d) * B + r0 + rc) = u.v;
    }
}

// -------- top-K on bf16 sim: moment-threshold + bisection + parallel rank select -----
__global__ __launch_bounds__(256) void k_topk2(const unsigned short* __restrict__ S,
                                               int* __restrict__ topk, int r0) {
    __shared__ float fs[4], fs2[4];
    __shared__ int cslot[2][4];
    __shared__ int islot[4];
    __shared__ unsigned long long buf[128];
    __shared__ int ccount;
    int li = blockIdx.x, tid = threadIdx.x;
    int i = r0 + li;
    const unsigned short* rp = S + (size_t)li * B;

    unsigned int key[32];
    float sum = 0.0f, sumsq = 0.0f;
#pragma unroll
    for (int j16 = 0; j16 < 4; j16++) {
        int4 v = *(const int4*)(rp + j16 * 2048 + tid * 8);
        const unsigned short* s8 = (const unsigned short*)&v;
#pragma unroll
        for (int q = 0; q < 8; q++) {
            int col = j16 * 2048 + tid * 8 + q;
            bool self = (col == i);
            unsigned int bits = ((unsigned int)s8[q]) << 16;
            float vv = self ? 0.0f : __builtin_bit_cast(float, bits);
            sum += vv;
            sumsq += vv * vv;
            unsigned int k = bits ^ ((bits & 0x80000000u) ? 0xFFFFFFFFu : 0x80000000u);
            key[j16 * 8 + q] = self ? 0u : k;
        }
    }

    float s1 = waveReduceSum(sum);
    float s2 = waveReduceSum(sumsq);
    int lane = tid & 63, wv = tid >> 6;
    if (lane == 0) { fs[wv] = s1; fs2[wv] = s2; }
    if (tid == 0) ccount = 0;
    __syncthreads();
    float S1 = fs[0] + fs[1] + fs[2] + fs[3];
    float S2 = fs2[0] + fs2[1] + fs2[2] + fs2[3];
    float mu = S1 * (1.0f / 8192.0f);
    float var = fmaxf(S2 * (1.0f / 8192.0f) - mu * mu, 0.0f);
    float sg = sqrtf(var);

    unsigned int klo = 0u, khi = 0xFFFFFFFFu;
    unsigned int T = 0;
    bool found = false;
    float z = 2.4f;
    for (int it = 0; it < 48; ++it) {
        unsigned int kt;
        if (it < 8) {
            float tf = mu + z * sg;
            unsigned int u = __builtin_bit_cast(unsigned int, tf);
            kt = u ^ ((u & 0x80000000u) ? 0xFFFFFFFFu : 0x80000000u);
            if (kt <= klo || kt >= khi) kt = klo + ((khi - klo) >> 1);
        } else {
            kt = klo + ((khi - klo) >> 1);
        }
        if (kt == klo) break;
        int c = 0;
#pragma unroll
        for (int j = 0; j < 32; j++) c += (key[j] > kt) ? 1 : 0;
        c = waveReduceSumI(c);
        if (lane == 0) cslot[it & 1][wv] = c;
        __syncthreads();
        int tot = cslot[it & 1][0] + cslot[it & 1][1] + cslot[it & 1][2] + cslot[it & 1][3];
        if (tot >= KNN && tot <= 128) { T = kt; found = true; break; }
        if (tot < KNN) { khi = kt; z -= 0.3f; }
        else          { klo = kt; z += 0.3f; }
    }
    if (!found) T = khi;
    __syncthreads();

#pragma unroll
    for (int j16 = 0; j16 < 4; j16++) {
#pragma unroll
        for (int q = 0; q < 8; q++) {
            int j = j16 * 8 + q;
            if (key[j] > T) {
                int p = atomicAdd(&ccount, 1);
                if (p < 128) {
                    int col = j16 * 2048 + tid * 8 + q;
                    buf[p] = ((unsigned long long)key[j] << 13) |
                             (unsigned long long)(8191 - col);
                }
            }
        }
    }
    __syncthreads();
    int C = ccount < 128 ? ccount : 128;

    if (tid < C) {
        unsigned long long my = buf[tid];
        int rank = 0;
        for (int j = 0; j < C; j++) rank += (buf[j] > my) ? 1 : 0;
        if (rank < KNN) topk[(size_t)i * KNN + rank] = 8191 - (int)(my & 0x1FFFull);
    }
    __syncthreads();

    if (C < KNN) {
        int last = -1;
        for (int it = C; it < KNN; ++it) {
            int best = 0x7fffffff;
#pragma unroll
            for (int j16 = 0; j16 < 4; j16++) {
#pragma unroll
                for (int q = 0; q < 8; q++) {
                    int j = j16 * 8 + q;
                    int col = j16 * 2048 + tid * 8 + q;
                    if (key[j] == T && col > last && col < best) best = col;
                }
            }
#pragma unroll
            for (int off = 32; off; off >>= 1) {
                int o = __shfl_down(best, off);
                best = (o < best) ? o : best;
            }
            if ((tid & 63) == 0) islot[tid >> 6] = best;
            __syncthreads();
            best = min(min(islot[0], islot[1]), min(islot[2], islot[3]));
            if (tid == 0) topk[(size_t)i * KNN + it] = best;
            last = best;
            __syncthreads();
        }
    }
}

// ---------------- graph build ----------------
__global__ void k_zero2(int* __restrict__ a, int* __restrict__ b) {
    int i = blockIdx.x * 256 + threadIdx.x;
    a[i] = 0;
    b[i] = 0;
}

__global__ void k_count(const int* __restrict__ topk, int* __restrict__ indeg) {
    int e = blockIdx.x * 256 + threadIdx.x;
    atomicAdd(&indeg[topk[e]], 1);
}

__global__ __launch_bounds__(1024) void k_scan(const int* __restrict__ indeg,
                                               int* __restrict__ roff) {
    __shared__ int sums[1024];
    int tid = threadIdx.x;
    int base = tid * 8;
    int loc[8];
    int s = 0;
#pragma unroll
    for (int j = 0; j < 8; j++) { loc[j] = s; s += indeg[base + j]; }
    sums[tid] = s;
    __syncthreads();
    for (int off = 1; off < 1024; off <<= 1) {
        int v = (tid >= off) ? sums[tid - off] : 0;
        __syncthreads();
        sums[tid] += v;
        __syncthreads();
    }
    int prev = (tid > 0) ? sums[tid - 1] : 0;
#pragma unroll
    for (int j = 0; j < 8; j++) roff[base + j] = prev + loc[j];
    if (tid == 1023) roff[B] = sums[1023];
}

// dinv + fused gather weight wf = dinv * fscale
__global__ void k_dinv(const int* __restrict__ indeg, const float* __restrict__ fscale,
                       float* __restrict__ dinv, float* __restrict__ wf) {
    int i = blockIdx.x * 256 + threadIdx.x;
    float dg = (float)(KNN + indeg[i]);
    float dv = fminf(1.0f / sqrtf(dg), 1e6f);
    dinv[i] = dv;
    wf[i] = dv * fscale[i];
}

__global__ void k_fill(const int* __restrict__ topk, const int* __restrict__ roff,
                       int* __restrict__ fill, int* __restrict__ ridx) {
    int e = blockIdx.x * 256 + threadIdx.x;
    int dst = topk[e];
    int src = e >> 5;
    int pos = atomicAdd(&fill[dst], 1);
    ridx[roff[dst] + pos] = src;
}

// ------- SpMM 1: gathers int8 Fq (4 MB, L2-resident); fused weights wf -------
__global__ __launch_bounds__(128) void k_spmm1(const unsigned int* __restrict__ Fq,
                                               const float* __restrict__ wf,
                                               unsigned int* __restrict__ G1q,
                                               float* __restrict__ wg,
                                               const int* __restrict__ topk,
                                               const int* __restrict__ roff,
                                               const int* __restrict__ ridx,
                                               const float* __restrict__ dinv) {
    int i = blockIdx.x, tid = threadIdx.x;
    float a0 = 0, a1 = 0, a2 = 0, a3 = 0;
    const int* ti = topk + (size_t)i * KNN;
#pragma unroll
    for (int k8 = 0; k8 < KNN / 8; k8++) {
        int4 na = *(const int4*)(ti + k8 * 8);
        int4 nb = *(const int4*)(ti + k8 * 8 + 4);
        unsigned int q0 = Fq[(size_t)na.x * GROW + tid];
        unsigned int q1 = Fq[(size_t)na.y * GROW + tid];
        unsigned int q2 = Fq[(size_t)na.z * GROW + tid];
        unsigned int q3 = Fq[(size_t)na.w * GROW + tid];
        unsigned int q4 = Fq[(size_t)nb.x * GROW + tid];
        unsigned int q5 = Fq[(size_t)nb.y * GROW + tid];
        unsigned int q6 = Fq[(size_t)nb.z * GROW + tid];
        unsigned int q7 = Fq[(size_t)nb.w * GROW + tid];
        float w0 = wf[na.x], w1 = wf[na.y], w2 = wf[na.z], w3 = wf[na.w];
        float w4 = wf[nb.x], w5 = wf[nb.y], w6 = wf[nb.z], w7 = wf[nb.w];
        float4 p0 = qdec(q0), p1 = qdec(q1), p2 = qdec(q2), p3 = qdec(q3);
        float4 p4 = qdec(q4), p5 = qdec(q5), p6 = qdec(q6), p7 = qdec(q7);
        a0 += w0 * p0.x + w1 * p1.x + w2 * p2.x + w3 * p3.x +
              w4 * p4.x + w5 * p5.x + w6 * p6.x + w7 * p7.x;
        a1 += w0 * p0.y + w1 * p1.y + w2 * p2.y + w3 * p3.y +
              w4 * p4.y + w5 * p5.y + w6 * p6.y + w7 * p7.y;
        a2 += w0 * p0.z + w1 * p1.z + w2 * p2.z + w3 * p3.z +
              w4 * p4.z + w5 * p5.z + w6 * p6.z + w7 * p7.z;
        a3 += w0 * p0.w + w1 * p1.w + w2 * p2.w + w3 * p3.w +
              w4 * p4.w + w5 * p5.w + w6 * p6.w + w7 * p7.w;
    }
    int s = roff[i], e = roff[i + 1];
    int t = s;
    for (; t + 2 <= e; t += 2) {
        int j0 = ridx[t], j1 = ridx[t + 1];
        float w0 = wf[j0], w1 = wf[j1];
        float4 p0 = qdec(Fq[(size_t)j0 * GROW + tid]);
        float4 p1 = qdec(Fq[(size_t)j1 * GROW + tid]);
        a0 += w0 * p0.x + w1 * p1.x;
        a1 += w0 * p0.y + w1 * p1.y;
        a2 += w0 * p0.z + w1 * p1.z;
        a3 += w0 * p0.w + w1 * p1.w;
    }
    if (t < e) {
        int j0 = ridx[t];
        float w0 = wf[j0];
        float4 p0 = qdec(Fq[(size_t)j0 * GROW + tid]);
        a0 += w0 * p0.x; a1 += w0 * p0.y; a2 += w0 * p0.z; a3 += w0 * p0.w;
    }
    float wi = dinv[i];
    float g0 = wi * a0, g1 = wi * a1, g2 = wi * a2, g3 = wi * a3;

    float am = fmaxf(fmaxf(fabsf(g0), fabsf(g1)), fmaxf(fabsf(g2), fabsf(g3)));
    am = waveReduceMax(am);
    __shared__ float rm[2];
    if ((tid & 63) == 0) rm[tid >> 6] = am;
    __syncthreads();
    float amax = fmaxf(rm[0], rm[1]);
    if (tid == 0) wg[i] = wi * amax * (1.0f / 127.0f);  // dinv*gscale fused
    float se = (amax > 0.0f) ? 127.0f / amax : 0.0f;
    G1q[(size_t)i * GROW + tid] = qenc(g0, g1, g2, g3, se);
}

// ------- SpMM 2 fused with Yb build: gathers int8 G1q; fused weights wg -------
__global__ __launch_bounds__(128) void k_spmm2y(const unsigned int* __restrict__ G1q,
                                                const float* __restrict__ wg,
                                                const float* __restrict__ F,
                                                const float* __restrict__ invnf,
                                                unsigned short* __restrict__ Yb,
                                                const int* __restrict__ topk,
                                                const int* __restrict__ roff,
                                                const int* __restrict__ ridx,
                                                const float* __restrict__ dinv) {
    int i = blockIdx.x, tid = threadIdx.x;
    float a0 = 0, a1 = 0, a2 = 0, a3 = 0;
    const int* ti = topk + (size_t)i * KNN;
#pragma unroll
    for (int k8 = 0; k8 < KNN / 8; k8++) {
        int4 na = *(const int4*)(ti + k8 * 8);
        int4 nb = *(const int4*)(ti + k8 * 8 + 4);
        unsigned int q0 = G1q[(size_t)na.x * GROW + tid];
        unsigned int q1 = G1q[(size_t)na.y * GROW + tid];
        unsigned int q2 = G1q[(size_t)na.z * GROW + tid];
        unsigned int q3 = G1q[(size_t)na.w * GROW + tid];
        unsigned int q4 = G1q[(size_t)nb.x * GROW + tid];
        unsigned int q5 = G1q[(size_t)nb.y * GROW + tid];
        unsigned int q6 = G1q[(size_t)nb.z * GROW + tid];
        unsigned int q7 = G1q[(size_t)nb.w * GROW + tid];
        float w0 = wg[na.x], w1 = wg[na.y], w2 = wg[na.z], w3 = wg[na.w];
        float w4 = wg[nb.x], w5 = wg[nb.y], w6 = wg[nb.z], w7 = wg[nb.w];
        float4 p0 = qdec(q0), p1 = qdec(q1), p2 = qdec(q2), p3 = qdec(q3);
        float4 p4 = qdec(q4), p5 = qdec(q5), p6 = qdec(q6), p7 = qdec(q7);
        a0 += w0 * p0.x + w1 * p1.x + w2 * p2.x + w3 * p3.x +
              w4 * p4.x + w5 * p5.x + w6 * p6.x + w7 * p7.x;
        a1 += w0 * p0.y + w1 * p1.y + w2 * p2.y + w3 * p3.y +
              w4 * p4.y + w5 * p5.y + w6 * p6.y + w7 * p7.y;
        a2 += w0 * p0.z + w1 * p1.z + w2 * p2.z + w3 * p3.z +
              w4 * p4.z + w5 * p5.z + w6 * p6.z + w7 * p7.z;
        a3 += w0 * p0.w + w1 * p1.w + w2 * p2.w + w3 * p3.w +
              w4 * p4.w + w5 * p5.w + w6 * p6.w + w7 * p7.w;
    }
    int s = roff[i], e = roff[i + 1];
    int t = s;
    for (; t + 2 <= e; t += 2) {
        int j0 = ridx[t], j1 = ridx[t + 1];
        float w0 = wg[j0], w1 = wg[j1];
        float4 p0 = qdec(G1q[(size_t)j0 * GROW + tid]);
        float4 p1 = qdec(G1q[(size_t)j1 * GROW + tid]);
        a0 += w0 * p0.x + w1 * p1.x;
        a1 += w0 * p0.y + w1 * p1.y;
        a2 += w0 * p0.z + w1 * p1.z;
        a3 += w0 * p0.w + w1 * p1.w;
    }
    if (t < e) {
        int j0 = ridx[t];
        float w0 = wg[j0];
        float4 p0 = qdec(G1q[(size_t)j0 * GROW + tid]);
        a0 += w0 * p0.x; a1 += w0 * p0.y; a2 += w0 * p0.z; a3 += w0 * p0.w;
    }
    float wi = dinv[i];
    float g0 = wi * a0, g1 = wi * a1, g2 = wi * a2, g3 = wi * a3;

    float ss = g0 * g0 + g1 * g1 + g2 * g2 + g3 * g3;
    ss = waveReduceSum(ss);
    __shared__ float s2[2];
    if ((tid & 63) == 0) s2[tid >> 6] = ss;
    __syncthreads();
    float invng = 1.0f / fmaxf(sqrtf(s2[0] + s2[1]), 1e-12f);

    float4 f = ((const float4*)(F + (size_t)i * D))[tid];
    float inf_ = 10.0f * invnf[i];
    union { unsigned short s4[4]; int2 q; } u;
    u.s4[0] = f2bf(f.x * inf_ + g0 * invng);
    u.s4[1] = f2bf(f.y * inf_ + g1 * invng);
    u.s4[2] = f2bf(f.z * inf_ + g2 * invng);
    u.s4[3] = f2bf(f.w * inf_ + g3 * invng);
    *(int2*)(Yb + (size_t)i * D + tid * 4) = u.q;
}

// ------- register-resident online row softmax: fp16 logits in, bf16 weights out -----
__global__ __launch_bounds__(256) void k_softmax(unsigned short* __restrict__ chunk16,
                                                 int rowstride) {
    __shared__ float sm[4], sl[4];
    int li = blockIdx.x, tid = threadIdx.x;
    unsigned short* rp = chunk16 + (size_t)li * rowstride;
    float v[32];
    float mt = -FLT_MAX;
#pragma unroll
    for (int j16 = 0; j16 < 4; j16++) {
        int4 w = *(const int4*)(rp + j16 * 2048 + tid * 8);
        const unsigned short* s8 = (const unsigned short*)&w;
#pragma unroll
        for (int q = 0; q < 8; q++) {
            float f = h2f(s8[q]);
            v[j16 * 8 + q] = f;
            mt = fmaxf(mt, f);
        }
    }
    float l = 0.0f;
#pragma unroll
    for (int j = 0; j < 32; j++) {
        v[j] = __expf(v[j] - mt);
        l += v[j];
    }
    float m = mt, lw = l;
#pragma unroll
    for (int off = 32; off; off >>= 1) {
        float om = __shfl_down(m, off);
        float ol = __shfl_down(lw, off);
        float nm = fmaxf(m, om);
        lw = lw * __expf(m - nm) + ol * __expf(om - nm);
        m = nm;
    }
    if ((tid & 63) == 0) { sm[tid >> 6] = m; sl[tid >> 6] = lw; }
    __syncthreads();
    float M = fmaxf(fmaxf(sm[0], sm[1]), fmaxf(sm[2], sm[3]));
    float L = sl[0] * __expf(sm[0] - M) + sl[1] * __expf(sm[1] - M) +
              sl[2] * __expf(sm[2] - M) + sl[3] * __expf(sm[3] - M);
    float fct = __expf(mt - M) / L;
#pragma unroll
    for (int j16 = 0; j16 < 4; j16++) {
        union { unsigned short s[8]; int4 w; } u;
#pragma unroll
        for (int q = 0; q < 8; q++) u.s[q] = f2bf(v[j16 * 8 + q] * fct);
        *(int4*)(rp + j16 * 2048 + tid * 8) = u.w;
    }
}

extern "C" void kernel_launch(void* const* d_in, const int* in_sizes, int n_in,
                              void* d_out, int out_size, void* d_ws, size_t ws_size,
                              hipStream_t stream) {
    (void)in_sizes; (void)n_in; (void)out_size;
    const float* F = (const float*)d_in[0];
    float* out = (float*)d_out;

    char* ws = (char*)d_ws;
    size_t off = 0;
    auto take = [&](size_t bytes) -> void* {
        void* p = ws + off;
        off += (bytes + 255) & ~(size_t)255;
        return p;
    };
    float* invnf = (float*)take((size_t)B * 4);
    float* dinv = (float*)take((size_t)B * 4);
    float* fscale = (float*)take((size_t)B * 4);
    float* wf = (float*)take((size_t)B * 4);
    float* wg = (float*)take((size_t)B * 4);
    int* topk = (int*)take((size_t)B * KNN * 4);
    int* indeg = (int*)take((size_t)B * 4);
    int* roff = (int*)take((size_t)(B + 1) * 4);
    int* rfill = (int*)take((size_t)B * 4);
    int* ridx = (int*)take((size_t)B * KNN * 4);
    unsigned short* Xb = (unsigned short*)take((size_t)B * D * 2);
    unsigned int* Fq = (unsigned int*)take((size_t)B * GROW * 4);
    unsigned short* Yb = (unsigned short*)take((size_t)B * D * 2);
    unsigned short* FbT = (unsigned short*)take((size_t)D * B * 2);
    size_t fixed = off;

    int R = 4096;  // larger chunks = fewer serialized phases; auto-shrinks to fit ws
    if (ws_size > 0) {
        while (R > 128 && fixed + (size_t)R * B * 4 > ws_size) R >>= 1;
    } else {
        R = 1024;
    }
    float* chunk = (float*)(ws + fixed);
    unsigned int* G1q = (unsigned int*)out;  // d_out scratch: 4 MB of 16

    // split-K: fp16 partials in the upper 16 KB of each 32 KB chunk row.
    // SK=8 (measured best: SK=16 doubled partial-write traffic with no occupancy gain).
    int SK = 8;
    int ksplit = B / SK;
    bool use8 = (R % 256) == 0;

    // 1. Xb / Fq / fscale / invnf; FbT = bf16 F^T
    k_norm<<<B, 128, 0, stream>>>(F, Xb, Fq, fscale, invnf);
    dim3 gt(B / 64, D / 64);
    k_transpose<<<gt, 256, 0, stream>>>(F, FbT);

    // 2. chunked: sim = Xb Xb^T (bf16 out) + top-K on bf16
    for (int r0 = 0; r0 < B; r0 += R) {
        if (use8) {
            dim3 g8(B / 256, R / 256);
            k_mfma8<1><<<g8, 512, 0, stream>>>(Xb + (size_t)r0 * D, D, Xb, D, chunk, B, D);
        } else {
            dim3 g(B / 128, R / 128);
            k_mfma_nt<1><<<g, 256, 0, stream>>>(Xb + (size_t)r0 * D, D, Xb, D, chunk, B, 0, D);
        }
        k_topk2<<<R, 256, 0, stream>>>((const unsigned short*)chunk, topk, r0);
    }

    // 3. graph build
    k_zero2<<<B / 256, 256, 0, stream>>>(indeg, rfill);
    k_count<<<B * KNN / 256, 256, 0, stream>>>(topk, indeg);
    k_scan<<<1, 1024, 0, stream>>>(indeg, roff);
    k_dinv<<<B / 256, 256, 0, stream>>>(indeg, fscale, dinv, wf);
    k_fill<<<B * KNN / 256, 256, 0, stream>>>(topk, roff, rfill, ridx);

    // 4. G1q = A_hat Fq (int8 tables, L2-resident); Yb = 10*Xhat + normalize(A_hat G1q)
    k_spmm1<<<B, 128, 0, stream>>>(Fq, wf, G1q, wg, topk, roff, ridx, dinv);
    k_spmm2y<<<B, 128, 0, stream>>>(G1q, wg, F, invnf, Yb, topk, roff, ridx, dinv);

    // 5. chunked: logits = Xb @ Yb^T (fp16 out, first 16KB of each 32KB row)
    //    -> softmax (fp16 in, bf16 weights in place)
    //    -> split-K final GEMM with fp16 partials (upper 16KB) -> fp32 reduce
    for (int r0 = 0; r0 < B; r0 += R) {
        if (use8) {
            dim3 g8(B / 256, R / 256);
            k_mfma8<2><<<g8, 512, 0, stream>>>(Xb + (size_t)r0 * D, D, Yb, D, chunk,
                                               2 * B, D);
        } else {
            dim3 g(B / 128, R / 128);
            k_mfma_nt<2><<<g, 256, 0, stream>>>(Xb + (size_t)r0 * D, D, Yb, D, chunk,
                                                2 * B, 0, D);
        }
        k_softmax<<<R, 256, 0, stream>>>((unsigned short*)chunk, 2 * B);
        unsigned short* part16 = (unsigned short*)chunk + 8192;  // upper 16KB of rows
        dim3 gf(D / 128, R / 128, SK);
        k_mfma_nt<2><<<gf, 256, 0, stream>>>((const unsigned short*)chunk, 2 * B, FbT, B,
                                             part16, 2 * B, D, ksplit);
        k_redh<<<R / 2, 256, 0, stream>>>(part16, out + (size_t)r0 * D, SK);
    }
}

// Round 23
// 456.167 us; speedup vs baseline: 1.0799x; 1.0492x over previous
//
#include <hip/hip_runtime.h>
#include <hip/hip_bf16.h>
#include <float.h>
#include <math.h>

constexpr int B = 8192;
constexpr int D = 512;
constexpr int KNN = 32;
constexpr int GROW = D / 4;  // packed int8x4 words per row

typedef __attribute__((ext_vector_type(8))) short bhalf8;
typedef __attribute__((ext_vector_type(4))) float floatx4;

#if defined(__has_builtin)
#if __has_builtin(__builtin_amdgcn_global_load_lds)
#define HAS_GLD 1
#else
#define HAS_GLD 0
#endif
#else
#define HAS_GLD 0
#endif

__device__ __forceinline__ unsigned short f2bf(float f) {
    __hip_bfloat16 h = __float2bfloat16(f);
    return __builtin_bit_cast(unsigned short, h);
}

__device__ __forceinline__ float bf2f(unsigned short u) {
    unsigned int x = ((unsigned int)u) << 16;
    return __builtin_bit_cast(float, x);
}

__device__ __forceinline__ unsigned short f2h(float f) {
    _Float16 h = (_Float16)f;
    return __builtin_bit_cast(unsigned short, h);
}

__device__ __forceinline__ float h2f(unsigned short u) {
    _Float16 h = __builtin_bit_cast(_Float16, u);
    return (float)h;
}

__device__ __forceinline__ float waveReduceSum(float v) {
#pragma unroll
    for (int off = 32; off; off >>= 1) v += __shfl_down(v, off);
    return v;
}

__device__ __forceinline__ float waveReduceMax(float v) {
#pragma unroll
    for (int off = 32; off; off >>= 1) v = fmaxf(v, __shfl_down(v, off));
    return v;
}

__device__ __forceinline__ int waveReduceSumI(int v) {
#pragma unroll
    for (int off = 32; off; off >>= 1) v += __shfl_down(v, off);
    return v;
}

// decode packed int8x4 -> float4 (linear quant; scale folded into gather weight)
__device__ __forceinline__ float4 qdec(unsigned int w) {
    float4 r;
    r.x = (float)((int)(w << 24) >> 24);
    r.y = (float)((int)(w << 16) >> 24);
    r.z = (float)((int)(w << 8) >> 24);
    r.w = (float)((int)w >> 24);
    return r;
}

__device__ __forceinline__ unsigned int qenc(float a, float b, float c, float d, float se) {
    int qx = (int)rintf(a * se); qx = max(-127, min(127, qx));
    int qy = (int)rintf(b * se); qy = max(-127, min(127, qy));
    int qz = (int)rintf(c * se); qz = max(-127, min(127, qz));
    int qw = (int)rintf(d * se); qw = max(-127, min(127, qw));
    return (unsigned int)(qx & 0xff) | ((unsigned int)(qy & 0xff) << 8) |
           ((unsigned int)(qz & 0xff) << 16) | ((unsigned int)(qw & 0xff) << 24);
}

// stage one 16B chunk of a 128x32-bf16 tile (linear LDS, 64B rows). (128^2 kernel)
__device__ __forceinline__ void stage_chunk(const unsigned short* __restrict__ g,
                                            char* __restrict__ lds_tile, int c) {
#if HAS_GLD
    char* wavebase = lds_tile + (size_t)(c & ~63) * 16;
    __builtin_amdgcn_global_load_lds((const __attribute__((address_space(1))) void*)g,
                                     (__attribute__((address_space(3))) void*)wavebase,
                                     16, 0, 0);
#else
    *(int4*)(lds_tile + (size_t)c * 16) = *(const int4*)g;
#endif
}

// C-write helper: OUTMODE 0=fp32, 1=bf16, 2=fp16. ldc in elements of the out type.
template <int OUTMODE>
__device__ __forceinline__ void cwrite(void* Cv, size_t idx, float v) {
    if (OUTMODE == 0) ((float*)Cv)[idx] = v;
    else if (OUTMODE == 1) ((unsigned short*)Cv)[idx] = f2bf(v);
    else ((unsigned short*)Cv)[idx] = f2h(v);
}

// ================= 8-phase 256x256 bf16 NT GEMM (m201-style) =================
// Split-K via blockIdx.z: K range [bz*ksplit, (bz+1)*ksplit), C += bz*zstride.
// For the final-GEMM config (gridDim = {2, ny, 8}) an XCD swizzle groups the 2
// x-blocks sharing an A-panel on one XCD: lid=(g%8)+8*((g/8)*2+bx), g=bz*ny+by.
template <int OUTMODE>
__global__ __launch_bounds__(512) void k_mfma8(
    const unsigned short* __restrict__ A, int lda,
    const unsigned short* __restrict__ Bm, int ldb,
    void* __restrict__ Cv, int ldc, int zstride, int ksplit) {
    __shared__ __align__(16) char lds[131072];
    constexpr int AOFF0 = 0, AOFF1 = 32768, BOFF0 = 65536, BOFF1 = 98304;

    int tid = threadIdx.x;
    int lane = tid & 63;
    int wid = tid >> 6;
    int wm = (wid >> 2) * 128;
    int wn = (wid & 3) * 64;
    int lrow = lane & 15;
    int khi = lane >> 4;
    int lk7 = lane & 7;

    int bx = blockIdx.x, by = blockIdx.y, bz = blockIdx.z;
    int ny = gridDim.y;
    if (gridDim.x == 2 && gridDim.z == 8) {
        int lid = bx + 2 * (by + ny * bz);  // hw linear id (x fastest)
        int xcd = lid & 7;
        int h = lid >> 3;
        bx = h & 1;
        int g = (h >> 1) * 8 + xcd;  // A-panel key, g < 8*ny
        by = g % ny;
        bz = g / ny;
    }
    int gm = by * 256, gn = bx * 256;
    int kbeg = bz * ksplit;
    size_t zoff = (size_t)bz * zstride;

    floatx4 zero4 = {0.0f, 0.0f, 0.0f, 0.0f};
    floatx4 acc[8][4];
#pragma unroll
    for (int m = 0; m < 8; m++)
#pragma unroll
        for (int n = 0; n < 4; n++) acc[m][n] = zero4;
    bhalf8 bfrag[4][2];

    auto stage_half = [&](const unsigned short* __restrict__ src, int ld,
                          int rowg0, int k0, int ldsbase) {
#pragma unroll
        for (int rd = 0; rd < 2; rd++) {
            int idx = rd * 512 + tid;
            int r = idx >> 3;
            int s = (idx & 7) ^ (r & 7);
            const unsigned short* g = src + (size_t)(rowg0 + r) * ld + k0 + s * 8;
#if HAS_GLD
            char* wb = lds + ldsbase + rd * 8192 + (tid >> 6) * 1024;
            __builtin_amdgcn_global_load_lds(
                (const __attribute__((address_space(1))) void*)g,
                (__attribute__((address_space(3))) void*)wb, 16, 0, 0);
#else
            *(int4*)(lds + ldsbase + (size_t)idx * 16) = *(const int4*)g;
#endif
        }
    };
    auto rdA = [&](int bufoff, int mf, int kk) -> bhalf8 {
        int r = wm + mf * 16 + lrow;
        int slot = ((kk << 2) + khi) ^ lk7;
        return *(const bhalf8*)(lds + bufoff + r * 128 + slot * 16);
    };
    auto rdB = [&](int bufoff, int nf, int kk) -> bhalf8 {
        int r = wn + nf * 16 + lrow;
        int slot = ((kk << 2) + khi) ^ lk7;
        return *(const bhalf8*)(lds + bufoff + r * 128 + slot * 16);
    };

    stage_half(A, lda, gm, kbeg, AOFF0);
    stage_half(A, lda, gm + 128, kbeg, AOFF0 + 16384);
    stage_half(Bm, ldb, gn, kbeg, BOFF0);
    stage_half(Bm, ldb, gn + 128, kbeg, BOFF0 + 16384);
    stage_half(Bm, ldb, gn, kbeg + 64, BOFF1);
    stage_half(Bm, ldb, gn + 128, kbeg + 64, BOFF1 + 16384);
    asm volatile("s_waitcnt vmcnt(4)" ::: "memory");
    __builtin_amdgcn_s_barrier();

#define PH(mq, AO, BO, STAGE_STMT, TAIL_STMT)                                      \
    {                                                                              \
        if ((mq) == 0) {                                                           \
            _Pragma("unroll") for (int nf = 0; nf < 4; nf++) {                     \
                bfrag[nf][0] = rdB((BO), nf, 0);                                   \
                bfrag[nf][1] = rdB((BO), nf, 1);                                   \
            }                                                                      \
        }                                                                          \
        bhalf8 a00 = rdA((AO), 2 * (mq), 0);                                       \
        bhalf8 a01 = rdA((AO), 2 * (mq), 1);                                       \
        bhalf8 a10 = rdA((AO), 2 * (mq) + 1, 0);                                   \
        bhalf8 a11 = rdA((AO), 2 * (mq) + 1, 1);                                   \
        STAGE_STMT;                                                                \
        __builtin_amdgcn_s_barrier();                                              \
        asm volatile("s_waitcnt lgkmcnt(0)" ::: "memory");                         \
        __builtin_amdgcn_sched_barrier(0);                                         \
        __builtin_amdgcn_s_setprio(1);                                             \
        _Pragma("unroll") for (int nf = 0; nf < 4; nf++) {                         \
            acc[2 * (mq)][nf] = __builtin_amdgcn_mfma_f32_16x16x32_bf16(           \
                a00, bfrag[nf][0], acc[2 * (mq)][nf], 0, 0, 0);                    \
            acc[2 * (mq) + 1][nf] = __builtin_amdgcn_mfma_f32_16x16x32_bf16(       \
                a10, bfrag[nf][0], acc[2 * (mq) + 1][nf], 0, 0, 0);                \
        }                                                                          \
        _Pragma("unroll") for (int nf = 0; nf < 4; nf++) {                         \
            acc[2 * (mq)][nf] = __builtin_amdgcn_mfma_f32_16x16x32_bf16(           \
                a01, bfrag[nf][1], acc[2 * (mq)][nf], 0, 0, 0);                    \
            acc[2 * (mq) + 1][nf] = __builtin_amdgcn_mfma_f32_16x16x32_bf16(       \
                a11, bfrag[nf][1], acc[2 * (mq) + 1][nf], 0, 0, 0);                \
        }                                                                          \
        __builtin_amdgcn_s_setprio(0);                                             \
        TAIL_STMT;                                                                 \
        __builtin_amdgcn_s_barrier();                                              \
    }

    int iters = ksplit >> 7;
    for (int it = 0; it < iters; ++it) {
        bool lastI = (it == iters - 1);
        int kodd = kbeg + ((2 * it + 1) << 6);
        int kne = kbeg + ((2 * it + 2) << 6);
        int kno = kbeg + ((2 * it + 3) << 6);
        PH(0, AOFF0, BOFF0, stage_half(A, lda, gm, kodd, AOFF1), );
        PH(1, AOFF0, BOFF0, stage_half(A, lda, gm + 128, kodd, AOFF1 + 16384), );
        PH(2, AOFF0, BOFF0, if (!lastI) stage_half(Bm, ldb, gn, kne, BOFF0), );
        PH(3, AOFF0, BOFF0, if (!lastI) stage_half(Bm, ldb, gn + 128, kne, BOFF0 + 16384),
           if (lastI) { asm volatile("s_waitcnt vmcnt(0)" ::: "memory"); } else {
               asm volatile("s_waitcnt vmcnt(4)" ::: "memory"); });
        PH(0, AOFF1, BOFF1, if (!lastI) stage_half(A, lda, gm, kne, AOFF0), );
        PH(1, AOFF1, BOFF1, if (!lastI) stage_half(A, lda, gm + 128, kne, AOFF0 + 16384), );
        PH(2, AOFF1, BOFF1, if (!lastI) stage_half(Bm, ldb, gn, kno, BOFF1), );
        PH(3, AOFF1, BOFF1, if (!lastI) stage_half(Bm, ldb, gn + 128, kno, BOFF1 + 16384),
           if (lastI) { asm volatile("s_waitcnt vmcnt(0)" ::: "memory"); } else {
               asm volatile("s_waitcnt vmcnt(4)" ::: "memory"); });
    }
#undef PH

#pragma unroll
    for (int mf = 0; mf < 8; mf++) {
#pragma unroll
        for (int nf = 0; nf < 4; nf++) {
            int cc = gn + wn + nf * 16 + lrow;
#pragma unroll
            for (int q = 0; q < 4; q++) {
                int r = gm + wm + mf * 16 + khi * 4 + q;
                cwrite<OUTMODE>(Cv, zoff + (size_t)r * ldc + cc, acc[mf][nf][q]);
            }
        }
    }
}

// ---------------- bf16 MFMA GEMM, NT form (128^2; fallback for small R) ----------
template <int OUTMODE>
__global__ __launch_bounds__(256, 2) void k_mfma_nt(
    const unsigned short* __restrict__ A, int lda,
    const unsigned short* __restrict__ B1, int ldb,
    void* __restrict__ Cv, int ldc, int zstride, int ksplit) {
    __shared__ __align__(16) char smem[2 * 8192];
    char* Asm = smem;
    char* B1sm = smem + 8192;

    int tid = threadIdx.x;
    int lane = tid & 63;
    int wid = tid >> 6;
    int wm = (wid >> 1) * 64, wn = (wid & 1) * 64;
    int lrow = lane & 15;
    int kh = lane >> 4;

    int bx = blockIdx.x, by = blockIdx.y, bz = blockIdx.z;
    int ny = gridDim.y;
    if (gridDim.x == 4 && gridDim.z >= 8 && ((ny * gridDim.z) & 7) == 0) {
        int lid = bx + 4 * (by + ny * bz);
        int xcd = lid & 7;
        int h = lid >> 3;
        bx = h & 3;
        int g = (h >> 2) * 8 + xcd;
        by = g % ny;
        bz = g / ny;
    }
    int gm = by * 128, gn = bx * 128;
    int kbeg = bz * ksplit;
    size_t zoff = (size_t)bz * zstride;

    floatx4 zero4 = {0.0f, 0.0f, 0.0f, 0.0f};
    floatx4 acc1[4][4];
#pragma unroll
    for (int m = 0; m < 4; m++)
#pragma unroll
        for (int n = 0; n < 4; n++) acc1[m][n] = zero4;

    for (int k0 = kbeg; k0 < kbeg + ksplit; k0 += 32) {
        __syncthreads();
#pragma unroll
        for (int p = 0; p < 2; p++) {
            int c = p * 256 + tid;
            int row = c >> 2;
            int col = (c & 3) * 8;
            stage_chunk(A + (size_t)(gm + row) * lda + k0 + col, Asm, c);
            stage_chunk(B1 + (size_t)(gn + row) * ldb + k0 + col, B1sm, c);
        }
        __syncthreads();

        bhalf8 a[4];
#pragma unroll
        for (int m = 0; m < 4; m++)
            a[m] = *(const bhalf8*)(Asm + (wm + m * 16 + lrow) * 64 + kh * 16);
#pragma unroll
        for (int n = 0; n < 4; n++) {
            bhalf8 b = *(const bhalf8*)(B1sm + (wn + n * 16 + lrow) * 64 + kh * 16);
#pragma unroll
            for (int m = 0; m < 4; m++)
                acc1[m][n] = __builtin_amdgcn_mfma_f32_16x16x32_bf16(a[m], b, acc1[m][n], 0, 0, 0);
        }
    }

#pragma unroll
    for (int m = 0; m < 4; m++) {
#pragma unroll
        for (int n = 0; n < 4; n++) {
            int cc = gn + wn + n * 16 + lrow;
#pragma unroll
            for (int q = 0; q < 4; q++) {
                int r = gm + wm + m * 16 + kh * 4 + q;
                cwrite<OUTMODE>(Cv, zoff + (size_t)r * ldc + cc, acc1[m][n][q]);
            }
        }
    }
}

// ---------------- split-K reduce over fp16 partials ----------------
// partial(z, lr, d) at P16 + lr*16384 + z*512 + d  (upper 16 KB of 32 KB chunk rows)
__global__ __launch_bounds__(256) void k_redh(const unsigned short* __restrict__ P16,
                                              float* __restrict__ outp, int SK) {
    int idx = blockIdx.x * 256 + threadIdx.x;
    int lr = idx >> 7;
    int d4 = (idx & 127) * 4;
    const unsigned short* base = P16 + (size_t)lr * 16384 + d4;
    float s0 = 0, s1 = 0, s2 = 0, s3 = 0;
    for (int p = 0; p < SK; p++) {
        int2 w = *(const int2*)(base + (size_t)p * 512);
        const unsigned short* h = (const unsigned short*)&w;
        s0 += h2f(h[0]); s1 += h2f(h[1]); s2 += h2f(h[2]); s3 += h2f(h[3]);
    }
    float4 o; o.x = s0; o.y = s1; o.z = s2; o.w = s3;
    *(float4*)(outp + (size_t)lr * 512 + d4) = o;
}

// ------- normalize rows of F -> bf16 Xb, int8 Fq + fscale, invnf -------
__global__ __launch_bounds__(128) void k_norm(const float* __restrict__ F,
                                              unsigned short* __restrict__ Xb,
                                              unsigned int* __restrict__ Fq,
                                              float* __restrict__ fscale,
                                              float* __restrict__ invnf) {
    int row = blockIdx.x, tid = threadIdx.x;
    float4 v = ((const float4*)(F + (size_t)row * D))[tid];
    float ss = v.x * v.x + v.y * v.y + v.z * v.z + v.w * v.w;
    float am = fmaxf(fmaxf(fabsf(v.x), fabsf(v.y)), fmaxf(fabsf(v.z), fabsf(v.w)));
    ss = waveReduceSum(ss);
    am = waveReduceMax(am);
    __shared__ float rs[2], rm[2];
    if ((tid & 63) == 0) { rs[tid >> 6] = ss; rm[tid >> 6] = am; }
    __syncthreads();
    float inv = 1.0f / fmaxf(sqrtf(rs[0] + rs[1]), 1e-12f);
    float amax = fmaxf(rm[0], rm[1]);
    if (tid == 0) { invnf[row] = inv; fscale[row] = amax * (1.0f / 127.0f); }
    union { unsigned short s[4]; int2 q; } ux;
    ux.s[0] = f2bf(v.x * inv); ux.s[1] = f2bf(v.y * inv);
    ux.s[2] = f2bf(v.z * inv); ux.s[3] = f2bf(v.w * inv);
    *(int2*)(Xb + (size_t)row * D + tid * 4) = ux.q;
    float se = (amax > 0.0f) ? 127.0f / amax : 0.0f;
    Fq[(size_t)row * GROW + tid] = qenc(v.x, v.y, v.z, v.w, se);
}

// ---------------- transpose F (fp32 BxD) -> FbT (bf16 DxB) ----------------
__global__ __launch_bounds__(256) void k_transpose(const float* __restrict__ F,
                                                   unsigned short* __restrict__ FbT) {
    __shared__ float t[64][65];
    int r0 = blockIdx.x * 64, d0 = blockIdx.y * 64;
    int tid = threadIdx.x;
#pragma unroll
    for (int p = 0; p < 4; p++) {
        int idx = p * 256 + tid;
        int r = idx >> 4, c4 = (idx & 15) * 4;
        float4 v = *(const float4*)(F + (size_t)(r0 + r) * D + d0 + c4);
        t[r][c4 + 0] = v.x; t[r][c4 + 1] = v.y; t[r][c4 + 2] = v.z; t[r][c4 + 3] = v.w;
    }
    __syncthreads();
#pragma unroll
    for (int p = 0; p < 2; p++) {
        int idx = p * 256 + tid;
        int d = idx >> 3, rc = (idx & 7) * 8;
        union { unsigned short s[8]; int4 v; } u;
#pragma unroll
        for (int j = 0; j < 8; j++) u.s[j] = f2bf(t[rc + j][d]);
        *(int4*)(FbT + (size_t)(d0 + d) * B + r0 + rc) = u.v;
    }
}

// -------- top-K on bf16 sim: moment-threshold + bisection + parallel rank select -----
__global__ __launch_bounds__(256) void k_topk2(const unsigned short* __restrict__ S,
                                               int* __restrict__ topk, int r0) {
    __shared__ float fs[4], fs2[4];
    __shared__ int cslot[2][4];
    __shared__ int islot[4];
    __shared__ unsigned long long buf[128];
    __shared__ int ccount;
    int li = blockIdx.x, tid = threadIdx.x;
    int i = r0 + li;
    const unsigned short* rp = S + (size_t)li * B;

    unsigned int key[32];
    float sum = 0.0f, sumsq = 0.0f;
#pragma unroll
    for (int j16 = 0; j16 < 4; j16++) {
        int4 v = *(const int4*)(rp + j16 * 2048 + tid * 8);
        const unsigned short* s8 = (const unsigned short*)&v;
#pragma unroll
        for (int q = 0; q < 8; q++) {
            int col = j16 * 2048 + tid * 8 + q;
            bool self = (col == i);
            unsigned int bits = ((unsigned int)s8[q]) << 16;
            float vv = self ? 0.0f : __builtin_bit_cast(float, bits);
            sum += vv;
            sumsq += vv * vv;
            unsigned int k = bits ^ ((bits & 0x80000000u) ? 0xFFFFFFFFu : 0x80000000u);
            key[j16 * 8 + q] = self ? 0u : k;
        }
    }

    float s1 = waveReduceSum(sum);
    float s2 = waveReduceSum(sumsq);
    int lane = tid & 63, wv = tid >> 6;
    if (lane == 0) { fs[wv] = s1; fs2[wv] = s2; }
    if (tid == 0) ccount = 0;
    __syncthreads();
    float S1 = fs[0] + fs[1] + fs[2] + fs[3];
    float S2 = fs2[0] + fs2[1] + fs2[2] + fs2[3];
    float mu = S1 * (1.0f / 8192.0f);
    float var = fmaxf(S2 * (1.0f / 8192.0f) - mu * mu, 0.0f);
    float sg = sqrtf(var);

    unsigned int klo = 0u, khi = 0xFFFFFFFFu;
    unsigned int T = 0;
    bool found = false;
    float z = 2.4f;
    for (int it = 0; it < 48; ++it) {
        unsigned int kt;
        if (it < 8) {
            float tf = mu + z * sg;
            unsigned int u = __builtin_bit_cast(unsigned int, tf);
            kt = u ^ ((u & 0x80000000u) ? 0xFFFFFFFFu : 0x80000000u);
            if (kt <= klo || kt >= khi) kt = klo + ((khi - klo) >> 1);
        } else {
            kt = klo + ((khi - klo) >> 1);
        }
        if (kt == klo) break;
        int c = 0;
#pragma unroll
        for (int j = 0; j < 32; j++) c += (key[j] > kt) ? 1 : 0;
        c = waveReduceSumI(c);
        if (lane == 0) cslot[it & 1][wv] = c;
        __syncthreads();
        int tot = cslot[it & 1][0] + cslot[it & 1][1] + cslot[it & 1][2] + cslot[it & 1][3];
        if (tot >= KNN && tot <= 128) { T = kt; found = true; break; }
        if (tot < KNN) { khi = kt; z -= 0.3f; }
        else          { klo = kt; z += 0.3f; }
    }
    if (!found) T = khi;
    __syncthreads();

#pragma unroll
    for (int j16 = 0; j16 < 4; j16++) {
#pragma unroll
        for (int q = 0; q < 8; q++) {
            int j = j16 * 8 + q;
            if (key[j] > T) {
                int p = atomicAdd(&ccount, 1);
                if (p < 128) {
                    int col = j16 * 2048 + tid * 8 + q;
                    buf[p] = ((unsigned long long)key[j] << 13) |
                             (unsigned long long)(8191 - col);
                }
            }
        }
    }
    __syncthreads();
    int C = ccount < 128 ? ccount : 128;

    if (tid < C) {
        unsigned long long my = buf[tid];
        int rank = 0;
        for (int j = 0; j < C; j++) rank += (buf[j] > my) ? 1 : 0;
        if (rank < KNN) topk[(size_t)i * KNN + rank] = 8191 - (int)(my & 0x1FFFull);
    }
    __syncthreads();

    if (C < KNN) {
        int last = -1;
        for (int it = C; it < KNN; ++it) {
            int best = 0x7fffffff;
#pragma unroll
            for (int j16 = 0; j16 < 4; j16++) {
#pragma unroll
                for (int q = 0; q < 8; q++) {
                    int j = j16 * 8 + q;
                    int col = j16 * 2048 + tid * 8 + q;
                    if (key[j] == T && col > last && col < best) best = col;
                }
            }
#pragma unroll
            for (int off = 32; off; off >>= 1) {
                int o = __shfl_down(best, off);
                best = (o < best) ? o : best;
            }
            if ((tid & 63) == 0) islot[tid >> 6] = best;
            __syncthreads();
            best = min(min(islot[0], islot[1]), min(islot[2], islot[3]));
            if (tid == 0) topk[(size_t)i * KNN + it] = best;
            last = best;
            __syncthreads();
        }
    }
}

// ---------------- graph build ----------------
__global__ void k_zero2(int* __restrict__ a, int* __restrict__ b) {
    int i = blockIdx.x * 256 + threadIdx.x;
    a[i] = 0;
    b[i] = 0;
}

__global__ void k_count(const int* __restrict__ topk, int* __restrict__ indeg) {
    int e = blockIdx.x * 256 + threadIdx.x;
    atomicAdd(&indeg[topk[e]], 1);
}

__global__ __launch_bounds__(1024) void k_scan(const int* __restrict__ indeg,
                                               int* __restrict__ roff) {
    __shared__ int sums[1024];
    int tid = threadIdx.x;
    int base = tid * 8;
    int loc[8];
    int s = 0;
#pragma unroll
    for (int j = 0; j < 8; j++) { loc[j] = s; s += indeg[base + j]; }
    sums[tid] = s;
    __syncthreads();
    for (int off = 1; off < 1024; off <<= 1) {
        int v = (tid >= off) ? sums[tid - off] : 0;
        __syncthreads();
        sums[tid] += v;
        __syncthreads();
    }
    int prev = (tid > 0) ? sums[tid - 1] : 0;
#pragma unroll
    for (int j = 0; j < 8; j++) roff[base + j] = prev + loc[j];
    if (tid == 1023) roff[B] = sums[1023];
}

// dinv + fused gather weight wf = dinv * fscale
__global__ void k_dinv(const int* __restrict__ indeg, const float* __restrict__ fscale,
                       float* __restrict__ dinv, float* __restrict__ wf) {
    int i = blockIdx.x * 256 + threadIdx.x;
    float dg = (float)(KNN + indeg[i]);
    float dv = fminf(1.0f / sqrtf(dg), 1e6f);
    dinv[i] = dv;
    wf[i] = dv * fscale[i];
}

__global__ void k_fill(const int* __restrict__ topk, const int* __restrict__ roff,
                       int* __restrict__ fill, int* __restrict__ ridx) {
    int e = blockIdx.x * 256 + threadIdx.x;
    int dst = topk[e];
    int src = e >> 5;
    int pos = atomicAdd(&fill[dst], 1);
    ridx[roff[dst] + pos] = src;
}

// ------- SpMM 1: gathers int8 Fq (4 MB, L2-resident); fused weights wf -------
__global__ __launch_bounds__(128) void k_spmm1(const unsigned int* __restrict__ Fq,
                                               const float* __restrict__ wf,
                                               unsigned int* __restrict__ G1q,
                                               float* __restrict__ wg,
                                               const int* __restrict__ topk,
                                               const int* __restrict__ roff,
                                               const int* __restrict__ ridx,
                                               const float* __restrict__ dinv) {
    int i = blockIdx.x, tid = threadIdx.x;
    float a0 = 0, a1 = 0, a2 = 0, a3 = 0;
    const int* ti = topk + (size_t)i * KNN;
#pragma unroll
    for (int k8 = 0; k8 < KNN / 8; k8++) {
        int4 na = *(const int4*)(ti + k8 * 8);
        int4 nb = *(const int4*)(ti + k8 * 8 + 4);
        unsigned int q0 = Fq[(size_t)na.x * GROW + tid];
        unsigned int q1 = Fq[(size_t)na.y * GROW + tid];
        unsigned int q2 = Fq[(size_t)na.z * GROW + tid];
        unsigned int q3 = Fq[(size_t)na.w * GROW + tid];
        unsigned int q4 = Fq[(size_t)nb.x * GROW + tid];
        unsigned int q5 = Fq[(size_t)nb.y * GROW + tid];
        unsigned int q6 = Fq[(size_t)nb.z * GROW + tid];
        unsigned int q7 = Fq[(size_t)nb.w * GROW + tid];
        float w0 = wf[na.x], w1 = wf[na.y], w2 = wf[na.z], w3 = wf[na.w];
        float w4 = wf[nb.x], w5 = wf[nb.y], w6 = wf[nb.z], w7 = wf[nb.w];
        float4 p0 = qdec(q0), p1 = qdec(q1), p2 = qdec(q2), p3 = qdec(q3);
        float4 p4 = qdec(q4), p5 = qdec(q5), p6 = qdec(q6), p7 = qdec(q7);
        a0 += w0 * p0.x + w1 * p1.x + w2 * p2.x + w3 * p3.x +
              w4 * p4.x + w5 * p5.x + w6 * p6.x + w7 * p7.x;
        a1 += w0 * p0.y + w1 * p1.y + w2 * p2.y + w3 * p3.y +
              w4 * p4.y + w5 * p5.y + w6 * p6.y + w7 * p7.y;
        a2 += w0 * p0.z + w1 * p1.z + w2 * p2.z + w3 * p3.z +
              w4 * p4.z + w5 * p5.z + w6 * p6.z + w7 * p7.z;
        a3 += w0 * p0.w + w1 * p1.w + w2 * p2.w + w3 * p3.w +
              w4 * p4.w + w5 * p5.w + w6 * p6.w + w7 * p7.w;
    }
    int s = roff[i], e = roff[i + 1];
    int t = s;
    for (; t + 2 <= e; t += 2) {
        int j0 = ridx[t], j1 = ridx[t + 1];
        float w0 = wf[j0], w1 = wf[j1];
        float4 p0 = qdec(Fq[(size_t)j0 * GROW + tid]);
        float4 p1 = qdec(Fq[(size_t)j1 * GROW + tid]);
        a0 += w0 * p0.x + w1 * p1.x;
        a1 += w0 * p0.y + w1 * p1.y;
        a2 += w0 * p0.z + w1 * p1.z;
        a3 += w0 * p0.w + w1 * p1.w;
    }
    if (t < e) {
        int j0 = ridx[t];
        float w0 = wf[j0];
        float4 p0 = qdec(Fq[(size_t)j0 * GROW + tid]);
        a0 += w0 * p0.x; a1 += w0 * p0.y; a2 += w0 * p0.z; a3 += w0 * p0.w;
    }
    float wi = dinv[i];
    float g0 = wi * a0, g1 = wi * a1, g2 = wi * a2, g3 = wi * a3;

    float am = fmaxf(fmaxf(fabsf(g0), fabsf(g1)), fmaxf(fabsf(g2), fabsf(g3)));
    am = waveReduceMax(am);
    __shared__ float rm[2];
    if ((tid & 63) == 0) rm[tid >> 6] = am;
    __syncthreads();
    float amax = fmaxf(rm[0], rm[1]);
    if (tid == 0) wg[i] = wi * amax * (1.0f / 127.0f);  // dinv*gscale fused
    float se = (amax > 0.0f) ? 127.0f / amax : 0.0f;
    G1q[(size_t)i * GROW + tid] = qenc(g0, g1, g2, g3, se);
}

// ------- SpMM 2 fused with Yb build: gathers int8 G1q; fused weights wg -------
__global__ __launch_bounds__(128) void k_spmm2y(const unsigned int* __restrict__ G1q,
                                                const float* __restrict__ wg,
                                                const float* __restrict__ F,
                                                const float* __restrict__ invnf,
                                                unsigned short* __restrict__ Yb,
                                                const int* __restrict__ topk,
                                                const int* __restrict__ roff,
                                                const int* __restrict__ ridx,
                                                const float* __restrict__ dinv) {
    int i = blockIdx.x, tid = threadIdx.x;
    float a0 = 0, a1 = 0, a2 = 0, a3 = 0;
    const int* ti = topk + (size_t)i * KNN;
#pragma unroll
    for (int k8 = 0; k8 < KNN / 8; k8++) {
        int4 na = *(const int4*)(ti + k8 * 8);
        int4 nb = *(const int4*)(ti + k8 * 8 + 4);
        unsigned int q0 = G1q[(size_t)na.x * GROW + tid];
        unsigned int q1 = G1q[(size_t)na.y * GROW + tid];
        unsigned int q2 = G1q[(size_t)na.z * GROW + tid];
        unsigned int q3 = G1q[(size_t)na.w * GROW + tid];
        unsigned int q4 = G1q[(size_t)nb.x * GROW + tid];
        unsigned int q5 = G1q[(size_t)nb.y * GROW + tid];
        unsigned int q6 = G1q[(size_t)nb.z * GROW + tid];
        unsigned int q7 = G1q[(size_t)nb.w * GROW + tid];
        float w0 = wg[na.x], w1 = wg[na.y], w2 = wg[na.z], w3 = wg[na.w];
        float w4 = wg[nb.x], w5 = wg[nb.y], w6 = wg[nb.z], w7 = wg[nb.w];
        float4 p0 = qdec(q0), p1 = qdec(q1), p2 = qdec(q2), p3 = qdec(q3);
        float4 p4 = qdec(q4), p5 = qdec(q5), p6 = qdec(q6), p7 = qdec(q7);
        a0 += w0 * p0.x + w1 * p1.x + w2 * p2.x + w3 * p3.x +
              w4 * p4.x + w5 * p5.x + w6 * p6.x + w7 * p7.x;
        a1 += w0 * p0.y + w1 * p1.y + w2 * p2.y + w3 * p3.y +
              w4 * p4.y + w5 * p5.y + w6 * p6.y + w7 * p7.y;
        a2 += w0 * p0.z + w1 * p1.z + w2 * p2.z + w3 * p3.z +
              w4 * p4.z + w5 * p5.z + w6 * p6.z + w7 * p7.z;
        a3 += w0 * p0.w + w1 * p1.w + w2 * p2.w + w3 * p3.w +
              w4 * p4.w + w5 * p5.w + w6 * p6.w + w7 * p7.w;
    }
    int s = roff[i], e = roff[i + 1];
    int t = s;
    for (; t + 2 <= e; t += 2) {
        int j0 = ridx[t], j1 = ridx[t + 1];
        float w0 = wg[j0], w1 = wg[j1];
        float4 p0 = qdec(G1q[(size_t)j0 * GROW + tid]);
        float4 p1 = qdec(G1q[(size_t)j1 * GROW + tid]);
        a0 += w0 * p0.x + w1 * p1.x;
        a1 += w0 * p0.y + w1 * p1.y;
        a2 += w0 * p0.z + w1 * p1.z;
        a3 += w0 * p0.w + w1 * p1.w;
    }
    if (t < e) {
        int j0 = ridx[t];
        float w0 = wg[j0];
        float4 p0 = qdec(G1q[(size_t)j0 * GROW + tid]);
        a0 += w0 * p0.x; a1 += w0 * p0.y; a2 += w0 * p0.z; a3 += w0 * p0.w;
    }
    float wi = dinv[i];
    float g0 = wi * a0, g1 = wi * a1, g2 = wi * a2, g3 = wi * a3;

    float ss = g0 * g0 + g1 * g1 + g2 * g2 + g3 * g3;
    ss = waveReduceSum(ss);
    __shared__ float s2[2];
    if ((tid & 63) == 0) s2[tid >> 6] = ss;
    __syncthreads();
    float invng = 1.0f / fmaxf(sqrtf(s2[0] + s2[1]), 1e-12f);

    float4 f = ((const float4*)(F + (size_t)i * D))[tid];
    float inf_ = 10.0f * invnf[i];
    union { unsigned short s4[4]; int2 q; } u;
    u.s4[0] = f2bf(f.x * inf_ + g0 * invng);
    u.s4[1] = f2bf(f.y * inf_ + g1 * invng);
    u.s4[2] = f2bf(f.z * inf_ + g2 * invng);
    u.s4[3] = f2bf(f.w * inf_ + g3 * invng);
    *(int2*)(Yb + (size_t)i * D + tid * 4) = u.q;
}

// ------- register-resident online row softmax: fp16 logits in, bf16 weights out -----
__global__ __launch_bounds__(256) void k_softmax(unsigned short* __restrict__ chunk16,
                                                 int rowstride) {
    __shared__ float sm[4], sl[4];
    int li = blockIdx.x, tid = threadIdx.x;
    unsigned short* rp = chunk16 + (size_t)li * rowstride;
    float v[32];
    float mt = -FLT_MAX;
#pragma unroll
    for (int j16 = 0; j16 < 4; j16++) {
        int4 w = *(const int4*)(rp + j16 * 2048 + tid * 8);
        const unsigned short* s8 = (const unsigned short*)&w;
#pragma unroll
        for (int q = 0; q < 8; q++) {
            float f = h2f(s8[q]);
            v[j16 * 8 + q] = f;
            mt = fmaxf(mt, f);
        }
    }
    float l = 0.0f;
#pragma unroll
    for (int j = 0; j < 32; j++) {
        v[j] = __expf(v[j] - mt);
        l += v[j];
    }
    float m = mt, lw = l;
#pragma unroll
    for (int off = 32; off; off >>= 1) {
        float om = __shfl_down(m, off);
        float ol = __shfl_down(lw, off);
        float nm = fmaxf(m, om);
        lw = lw * __expf(m - nm) + ol * __expf(om - nm);
        m = nm;
    }
    if ((tid & 63) == 0) { sm[tid >> 6] = m; sl[tid >> 6] = lw; }
    __syncthreads();
    float M = fmaxf(fmaxf(sm[0], sm[1]), fmaxf(sm[2], sm[3]));
    float L = sl[0] * __expf(sm[0] - M) + sl[1] * __expf(sm[1] - M) +
              sl[2] * __expf(sm[2] - M) + sl[3] * __expf(sm[3] - M);
    float fct = __expf(mt - M) / L;
#pragma unroll
    for (int j16 = 0; j16 < 4; j16++) {
        union { unsigned short s[8]; int4 w; } u;
#pragma unroll
        for (int q = 0; q < 8; q++) u.s[q] = f2bf(v[j16 * 8 + q] * fct);
        *(int4*)(rp + j16 * 2048 + tid * 8) = u.w;
    }
}

extern "C" void kernel_launch(void* const* d_in, const int* in_sizes, int n_in,
                              void* d_out, int out_size, void* d_ws, size_t ws_size,
                              hipStream_t stream) {
    (void)in_sizes; (void)n_in; (void)out_size;
    const float* F = (const float*)d_in[0];
    float* out = (float*)d_out;

    char* ws = (char*)d_ws;
    size_t off = 0;
    auto take = [&](size_t bytes) -> void* {
        void* p = ws + off;
        off += (bytes + 255) & ~(size_t)255;
        return p;
    };
    float* invnf = (float*)take((size_t)B * 4);
    float* dinv = (float*)take((size_t)B * 4);
    float* fscale = (float*)take((size_t)B * 4);
    float* wf = (float*)take((size_t)B * 4);
    float* wg = (float*)take((size_t)B * 4);
    int* topk = (int*)take((size_t)B * KNN * 4);
    int* indeg = (int*)take((size_t)B * 4);
    int* roff = (int*)take((size_t)(B + 1) * 4);
    int* rfill = (int*)take((size_t)B * 4);
    int* ridx = (int*)take((size_t)B * KNN * 4);
    unsigned short* Xb = (unsigned short*)take((size_t)B * D * 2);
    unsigned int* Fq = (unsigned int*)take((size_t)B * GROW * 4);
    unsigned short* Yb = (unsigned short*)take((size_t)B * D * 2);
    unsigned short* FbT = (unsigned short*)take((size_t)D * B * 2);
    size_t fixed = off;

    int R = 4096;  // larger chunks = fewer serialized phases; auto-shrinks to fit ws
    if (ws_size > 0) {
        while (R > 128 && fixed + (size_t)R * B * 4 > ws_size) R >>= 1;
    } else {
        R = 1024;
    }
    float* chunk = (float*)(ws + fixed);
    unsigned int* G1q = (unsigned int*)out;  // d_out scratch: 4 MB of 16

    // split-K: fp16 partials in the upper 16 KB of each 32 KB chunk row. SK=8.
    int SK = 8;
    int ksplit = B / SK;
    bool use8 = (R % 256) == 0;

    // 1. Xb / Fq / fscale / invnf; FbT = bf16 F^T
    k_norm<<<B, 128, 0, stream>>>(F, Xb, Fq, fscale, invnf);
    dim3 gt(B / 64, D / 64);
    k_transpose<<<gt, 256, 0, stream>>>(F, FbT);

    // 2. chunked: sim = Xb Xb^T (bf16 out) + top-K on bf16
    for (int r0 = 0; r0 < B; r0 += R) {
        if (use8) {
            dim3 g8(B / 256, R / 256);
            k_mfma8<1><<<g8, 512, 0, stream>>>(Xb + (size_t)r0 * D, D, Xb, D, chunk, B,
                                               0, D);
        } else {
            dim3 g(B / 128, R / 128);
            k_mfma_nt<1><<<g, 256, 0, stream>>>(Xb + (size_t)r0 * D, D, Xb, D, chunk, B, 0, D);
        }
        k_topk2<<<R, 256, 0, stream>>>((const unsigned short*)chunk, topk, r0);
    }

    // 3. graph build
    k_zero2<<<B / 256, 256, 0, stream>>>(indeg, rfill);
    k_count<<<B * KNN / 256, 256, 0, stream>>>(topk, indeg);
    k_scan<<<1, 1024, 0, stream>>>(indeg, roff);
    k_dinv<<<B / 256, 256, 0, stream>>>(indeg, fscale, dinv, wf);
    k_fill<<<B * KNN / 256, 256, 0, stream>>>(topk, roff, rfill, ridx);

    // 4. G1q = A_hat Fq (int8 tables, L2-resident); Yb = 10*Xhat + normalize(A_hat G1q)
    k_spmm1<<<B, 128, 0, stream>>>(Fq, wf, G1q, wg, topk, roff, ridx, dinv);
    k_spmm2y<<<B, 128, 0, stream>>>(G1q, wg, F, invnf, Yb, topk, roff, ridx, dinv);

    // 5. chunked: logits = Xb @ Yb^T (fp16 out, first 16KB of each 32KB row)
    //    -> softmax (fp16 in, bf16 weights in place)
    //    -> split-K final GEMM (8-phase 256^2, fp16 partials in upper 16KB) -> reduce
    for (int r0 = 0; r0 < B; r0 += R) {
        if (use8) {
            dim3 g8(B / 256, R / 256);
            k_mfma8<2><<<g8, 512, 0, stream>>>(Xb + (size_t)r0 * D, D, Yb, D, chunk,
                                               2 * B, 0, D);
        } else {
            dim3 g(B / 128, R / 128);
            k_mfma_nt<2><<<g, 256, 0, stream>>>(Xb + (size_t)r0 * D, D, Yb, D, chunk,
                                                2 * B, 0, D);
        }
        k_softmax<<<R, 256, 0, stream>>>((unsigned short*)chunk, 2 * B);
        unsigned short* part16 = (unsigned short*)chunk + 8192;  // upper 16KB of rows
        if (use8) {
            dim3 gf8(D / 256, R / 256, SK);
            k_mfma8<2><<<gf8, 512, 0, stream>>>((const unsigned short*)chunk, 2 * B, FbT,
                                                B, part16, 2 * B, 512, ksplit);
        } else {
            dim3 gf(D / 128, R / 128, SK);
            k_mfma_nt<2><<<gf, 256, 0, stream>>>((const unsigned short*)chunk, 2 * B, FbT,
                                                 B, part16, 2 * B, 512, ksplit);
        }
        k_redh<<<R / 2, 256, 0, stream>>>(part16, out + (size_t)r0 * D, SK);
    }
}